// Round 7
// baseline (910.958 us; speedup 1.0000x reference)
//
#include <hip/hip_runtime.h>
#include <math.h>

#define N_NODES 50000
#define N_EDGES 800000
#define NGRAPH  64
#define KEFF    576   // compressed agg width (768->576 via x_dst folding)

typedef short bf16x8 __attribute__((ext_vector_type(8)));
typedef float f32x4  __attribute__((ext_vector_type(4)));

__device__ inline unsigned short f2bf_rne(float f) {
  unsigned u = __float_as_uint(f);
  unsigned r = u + 0x7FFFu + ((u >> 16) & 1u);
  return (unsigned short)(r >> 16);
}
__device__ inline float bf2f(unsigned short h) {
  return __uint_as_float(((unsigned)h) << 16);
}

// ===================== setup kernels =====================

__global__ __launch_bounds__(256) void node_enc_kernel(
    const float* __restrict__ xin, const float* __restrict__ nw,
    const float* __restrict__ nb, float* __restrict__ x)
{
  __shared__ float xs[256];
  int tid = threadIdx.x;
  int base = blockIdx.x * 256;          // 4 nodes per block
  xs[tid] = xin[base + tid];
  __syncthreads();
  int r = tid >> 6, j = tid & 63;
  float acc = nb[j];
#pragma unroll
  for (int t = 0; t < 64; t++) acc = fmaf(xs[r * 64 + t], nw[t * 64 + j], acc);
  x[base + tid] = acc;
}

__global__ void count_kernel(const int* __restrict__ dst, int* __restrict__ cnt)
{
  int e = blockIdx.x * 256 + threadIdx.x;   // grid exactly covers E
  atomicAdd(&cnt[dst[e]], 1);
}

__global__ __launch_bounds__(256) void scan_a_kernel(
    const int* __restrict__ cnt, int* __restrict__ bsum)
{
  __shared__ int s[256];
  int i = blockIdx.x * 256 + threadIdx.x;
  s[threadIdx.x] = (i < N_NODES) ? cnt[i] : 0;
  __syncthreads();
  for (int off = 128; off > 0; off >>= 1) {
    if (threadIdx.x < off) s[threadIdx.x] += s[threadIdx.x + off];
    __syncthreads();
  }
  if (threadIdx.x == 0) bsum[blockIdx.x] = s[0];
}

__global__ __launch_bounds__(256) void scan_b_kernel(
    const int* __restrict__ bsum, int* __restrict__ boff)
{
  __shared__ int s[256];
  int tid = threadIdx.x;
  int v = (tid < 196) ? bsum[tid] : 0;
  s[tid] = v;
  __syncthreads();
  for (int off = 1; off < 256; off <<= 1) {
    int t = (tid >= off) ? s[tid - off] : 0;
    __syncthreads();
    s[tid] += t;
    __syncthreads();
  }
  boff[tid] = s[tid] - v;   // exclusive prefix of block sums
}

__global__ __launch_bounds__(256) void scan_c_kernel(
    const int* __restrict__ cnt, const int* __restrict__ boff,
    int* __restrict__ row_ptr)
{
  __shared__ int s[256];
  int tid = threadIdx.x;
  int i = blockIdx.x * 256 + tid;
  int v = (i < N_NODES) ? cnt[i] : 0;
  s[tid] = v;
  __syncthreads();
  for (int off = 1; off < 256; off <<= 1) {
    int t = (tid >= off) ? s[tid - off] : 0;
    __syncthreads();
    s[tid] += t;
    __syncthreads();
  }
  int incl = s[tid];
  int base = boff[blockIdx.x];
  if (i < N_NODES) row_ptr[i] = base + incl - v;
  if (i == N_NODES - 1) row_ptr[N_NODES] = base + incl;
}

__global__ void fill_kernel(const int* __restrict__ src, const int* __restrict__ dst,
                            int* __restrict__ cursor, int* __restrict__ srcs,
                            int* __restrict__ eids)
{
  int e = blockIdx.x * 256 + threadIdx.x;
  int d = dst[e];
  int pos = atomicAdd(&cursor[d], 1);
  srcs[pos] = src[e];
  eids[pos] = e;
}

__global__ __launch_bounds__(256) void deg_log_kernel(
    const int* __restrict__ cnt, float* __restrict__ log_deg,
    double* __restrict__ avgacc)
{
  __shared__ double sb[256];
  int i = blockIdx.x * 256 + threadIdx.x;
  double c = 0.0;
  if (i < N_NODES) {
    int d = cnt[i];
    int dc = d > 0 ? d : 1;
    log_deg[i] = logf((float)dc + 1.0f);         // log(degc + 1)
    c = (double)logf((float)d + 1.0f);           // avg uses raw deg
  }
  sb[threadIdx.x] = c;
  __syncthreads();
  for (int off = 128; off > 0; off >>= 1) {
    if (threadIdx.x < off) sb[threadIdx.x] += sb[threadIdx.x + off];
    __syncthreads();
  }
  if (threadIdx.x == 0) atomicAdd(avgacc, sb[0]);
}

__global__ void finalize_avg_kernel(const double* __restrict__ avgacc,
                                    float* __restrict__ avgf)
{
  *avgf = (float)(*avgacc / (double)N_NODES);
}

// graph node counts from sorted batch via binary search
__global__ void gbound_kernel(const int* __restrict__ batch, int* __restrict__ gcnt)
{
  __shared__ int sb[65];
  int g = threadIdx.x;  // 64 threads
  int lo = 0, hi = N_NODES;
  while (lo < hi) { int mid = (lo + hi) >> 1; if (batch[mid] < g) lo = mid + 1; else hi = mid; }
  sb[g] = lo;
  if (g == 0) sb[64] = N_NODES;
  __syncthreads();
  gcnt[g] = sb[g + 1] - sb[g];
}

// ===================== weight prep: fold + transpose + bf16 hi/lo split =====

__global__ __launch_bounds__(256) void wprep_kernel(
    const float* __restrict__ conv_w, unsigned short* __restrict__ wh,
    unsigned short* __restrict__ wl)
{
  int idx = blockIdx.x * 256 + threadIdx.x;   // 3*192*576 = 331776 = 1296*256
  int k = idx % 576;
  int c = (idx / 576) % 192;
  int l = idx / (576 * 192);
  int s = c >> 6, j = c & 63;
  const float* CW = conv_w + (size_t)l * 2304 * 64;
  float v;
  if (k < 64) {
    int base = s * 768 + k;
    v = CW[base * 64 + j] + CW[(base + 192) * 64 + j] + CW[(base + 384) * 64 + j];
  } else {
    const int srcseg[8] = {1, 2, 4, 5, 7, 8, 10, 11};
    int q = (k >> 6) - 1;
    int t = k & 63;
    v = CW[(s * 768 + srcseg[q] * 64 + t) * 64 + j];
  }
  unsigned short hh = f2bf_rne(v);
  wh[idx] = hh;
  wl[idx] = f2bf_rne(v - bf2f(hh));
}

__global__ void bprep_kernel(const float* __restrict__ conv_w, float* __restrict__ beff)
{
  int l = blockIdx.x;                 // 3 blocks x 192 threads
  int s = threadIdx.x >> 6, j = threadIdx.x & 63;
  const float* CW = conv_w + (size_t)l * 2304 * 64 + (size_t)(s * 768 + 576) * 64;
  float sum = 0.f;
#pragma unroll
  for (int t = 0; t < 64; t++) sum += CW[t * 64 + j];
  beff[(l * 3 + s) * 64 + j] = sum * 0.0031622776601683794f;   // sqrt(1e-5)
}

// ===================== e-segment aggregation (layer-invariant, once) ========
// 4 edges per iteration: lane-quad q holds edge (j+q)'s 16 attrs -> one
// full-wave gather; 4 independent chains (x2 sub-chains) for ILP.
// (R6 MFMA-encoder variant was neutral: per-tile scalar overhead dominates at
// deg~16. Keeping the simpler readlane form.)

__global__ __launch_bounds__(256) void agg_e_kernel(
    const float* __restrict__ eattr, const float* __restrict__ edge_w,
    const float* __restrict__ edge_b, const int* __restrict__ row_ptr,
    const int* __restrict__ eids,
    unsigned short* __restrict__ agg_h, unsigned short* __restrict__ agg_l)
{
  int lane = threadIdx.x & 63;
  int quad = lane >> 4, a16 = lane & 15;
  int n = blockIdx.x * 4 + (threadIdx.x >> 6);
  if (n >= N_NODES) return;
  float ew[16];
#pragma unroll
  for (int t = 0; t < 16; t++) ew[t] = edge_w[t * 64 + lane];
  float eb = edge_b[lane];
  int s0 = row_ptr[n], s1 = row_ptr[n + 1];
  float se = 0.f, qe = 0.f, mxe = -3.4e38f, mne = 3.4e38f;

  for (int j = s0; j < s1; j += 4) {
    int idx = j + quad;
    float av = 0.f;
    if (idx < s1) av = eattr[(size_t)eids[idx] * 16 + a16];
    unsigned au = __float_as_uint(av);
    float ea[4];
#pragma unroll
    for (int q = 0; q < 4; q++) {
      float c0 = eb, c1 = 0.f;
#pragma unroll
      for (int t = 0; t < 8; t++) {
        c0 = fmaf(__uint_as_float(__builtin_amdgcn_readlane(au, q * 16 + t)), ew[t], c0);
        c1 = fmaf(__uint_as_float(__builtin_amdgcn_readlane(au, q * 16 + 8 + t)), ew[8 + t], c1);
      }
      ea[q] = c0 + c1;
    }
    int rem = s1 - j;   // wave-uniform
#pragma unroll
    for (int q = 0; q < 4; q++) {
      if (q < rem) {
        se += ea[q]; qe = fmaf(ea[q], ea[q], qe);
        mxe = fmaxf(mxe, ea[q]); mne = fminf(mne, ea[q]);
      }
    }
  }

  int deg = s1 - s0;
  float inv = 1.0f / fmaxf((float)deg, 1.0f);
  bool has = deg > 0;
  float m_e = se * inv, ms_e = qe * inv;
  float sd_e = sqrtf(fmaxf(ms_e - m_e * m_e, 0.f) + 1e-5f);
  float mx_e = has ? mxe : 0.f, mn_e = has ? mne : 0.f;

  unsigned short* bh = agg_h + (size_t)n * KEFF;
  unsigned short* bl = agg_l + (size_t)n * KEFF;
#define W2(off, val) { float _v = (val); unsigned short _h = f2bf_rne(_v); \
                       bh[(off) + lane] = _h; bl[(off) + lane] = f2bf_rne(_v - bf2f(_h)); }
  W2(128, m_e); W2(256, mn_e); W2(384, mx_e); W2(512, sd_e);
#undef W2
}

// ===================== per-layer x-segment aggregation =====================
// x8 unroll: 8 gathers in flight, 4 rotating accumulator chains.

__global__ __launch_bounds__(256) void agg_x_kernel(
    const float* __restrict__ x, const int* __restrict__ srcs,
    const int* __restrict__ row_ptr,
    unsigned short* __restrict__ agg_h, unsigned short* __restrict__ agg_l)
{
  int lane = threadIdx.x & 63;
  int n = blockIdx.x * 4 + (threadIdx.x >> 6);
  if (n >= N_NODES) return;
  float xd = x[(size_t)n * 64 + lane];
  int s0 = row_ptr[n], s1 = row_ptr[n + 1];
  float sA = 0.f, sB = 0.f, sC = 0.f, sD = 0.f;
  float qA = 0.f, qB = 0.f, qC = 0.f, qD = 0.f;
  float mx0 = -3.4e38f, mx1 = -3.4e38f, mn0 = 3.4e38f, mn1 = 3.4e38f;
  int j = s0;
  for (; j + 7 < s1; j += 8) {
    int e0 = srcs[j],     e1 = srcs[j + 1], e2 = srcs[j + 2], e3 = srcs[j + 3];
    int e4 = srcs[j + 4], e5 = srcs[j + 5], e6 = srcs[j + 6], e7 = srcs[j + 7];
    float x0 = x[(size_t)e0 * 64 + lane];
    float x1 = x[(size_t)e1 * 64 + lane];
    float x2 = x[(size_t)e2 * 64 + lane];
    float x3 = x[(size_t)e3 * 64 + lane];
    float x4 = x[(size_t)e4 * 64 + lane];
    float x5 = x[(size_t)e5 * 64 + lane];
    float x6 = x[(size_t)e6 * 64 + lane];
    float x7 = x[(size_t)e7 * 64 + lane];
    sA += x0; sB += x1; sC += x2; sD += x3;
    sA += x4; sB += x5; sC += x6; sD += x7;
    qA = fmaf(x0, x0, qA); qB = fmaf(x1, x1, qB);
    qC = fmaf(x2, x2, qC); qD = fmaf(x3, x3, qD);
    qA = fmaf(x4, x4, qA); qB = fmaf(x5, x5, qB);
    qC = fmaf(x6, x6, qC); qD = fmaf(x7, x7, qD);
    mx0 = fmaxf(mx0, fmaxf(fmaxf(x0, x1), fmaxf(x2, x3)));
    mx1 = fmaxf(mx1, fmaxf(fmaxf(x4, x5), fmaxf(x6, x7)));
    mn0 = fminf(mn0, fminf(fminf(x0, x1), fminf(x2, x3)));
    mn1 = fminf(mn1, fminf(fminf(x4, x5), fminf(x6, x7)));
  }
  for (; j + 3 < s1; j += 4) {
    int e0 = srcs[j], e1 = srcs[j + 1], e2 = srcs[j + 2], e3 = srcs[j + 3];
    float x0 = x[(size_t)e0 * 64 + lane];
    float x1 = x[(size_t)e1 * 64 + lane];
    float x2 = x[(size_t)e2 * 64 + lane];
    float x3 = x[(size_t)e3 * 64 + lane];
    sA += x0; sB += x1; sC += x2; sD += x3;
    qA = fmaf(x0, x0, qA); qB = fmaf(x1, x1, qB);
    qC = fmaf(x2, x2, qC); qD = fmaf(x3, x3, qD);
    mx0 = fmaxf(mx0, fmaxf(x0, x1)); mx1 = fmaxf(mx1, fmaxf(x2, x3));
    mn0 = fminf(mn0, fminf(x0, x1)); mn1 = fminf(mn1, fminf(x2, x3));
  }
  for (; j < s1; j++) {
    float xa = x[(size_t)srcs[j] * 64 + lane];
    sA += xa; qA = fmaf(xa, xa, qA);
    mx0 = fmaxf(mx0, xa); mn0 = fminf(mn0, xa);
  }
  float sx = (sA + sB) + (sC + sD);
  float qx = (qA + qB) + (qC + qD);
  float mxx = fmaxf(mx0, mx1), mnx = fminf(mn0, mn1);

  int deg = s1 - s0;
  float inv = 1.0f / fmaxf((float)deg, 1.0f);
  bool has = deg > 0;
  float m_s = sx * inv, ms_s = qx * inv;
  float sd_s = sqrtf(fmaxf(ms_s - m_s * m_s, 0.f) + 1e-5f);
  float mx_s = has ? mxx : 0.f, mn_s = has ? mnx : 0.f;

  unsigned short* bh = agg_h + (size_t)n * KEFF;
  unsigned short* bl = agg_l + (size_t)n * KEFF;
#define W2(off, val) { float _v = (val); unsigned short _h = f2bf_rne(_v); \
                       bh[(off) + lane] = _h; bl[(off) + lane] = f2bf_rne(_v - bf2f(_h)); }
  W2(0,   has ? xd : 0.f);
  W2(64,  m_s); W2(192, mn_s); W2(320, mx_s); W2(448, sd_s);
#undef W2
}

// ===================== MFMA GEMM v3: LDS-free, barrier-free ================
// D = Ah*Bh + Al*Bh + Ah*Bl (split-bf16 ~ fp32). 256 thr / 4 waves, M=64,
// N=192; wave w owns cols {s*64 + w*16 + l15}. All MFMA fragments loaded
// DIRECTLY from global (16B/lane, 16B-aligned, row stride 1152B): B (442KB)
// stays hot in L2; A streams from LLC. No __syncthreads -> no barrier drain;
// waves pipeline loads against MFMA independently.

__global__ __launch_bounds__(256, 2) void gemm_kernel(
    const unsigned short* __restrict__ Ah, const unsigned short* __restrict__ Al,
    const unsigned short* __restrict__ Wh, const unsigned short* __restrict__ Wl,
    const float* __restrict__ beff, const float* __restrict__ bias,
    const float* __restrict__ log_deg, const float* __restrict__ avg_ptr,
    float* __restrict__ h, double* __restrict__ bnacc)
{
  int tid = threadIdx.x;
  int lane = tid & 63, w = tid >> 6;
  int quad = lane >> 4, l15 = lane & 15;
  int n0 = blockIdx.x * 64;

  // A fragment row pointers (4 row-frags of 16; row = n0 + i*16 + l15)
  const unsigned short* pah[4];
  const unsigned short* pal[4];
#pragma unroll
  for (int i = 0; i < 4; i++) {
    int an = n0 + i * 16 + l15;
    if (an >= N_NODES) an = N_NODES - 1;
    pah[i] = Ah + (size_t)an * KEFF;
    pal[i] = Al + (size_t)an * KEFF;
  }
  // B fragment col pointers (3 segments; col = s*64 + w*16 + l15)
  const unsigned short* pbh[3];
  const unsigned short* pbl[3];
#pragma unroll
  for (int s = 0; s < 3; s++) {
    int col = s * 64 + w * 16 + l15;
    pbh[s] = Wh + (size_t)col * KEFF;
    pbl[s] = Wl + (size_t)col * KEFF;
  }

  f32x4 acc[4][3] = {};

#pragma unroll 2
  for (int k0 = 0; k0 < KEFF; k0 += 32) {
    int ko = k0 + quad * 8;
    bf16x8 ahf[4], alf[4], bhf[3], blf[3];
#pragma unroll
    for (int i = 0; i < 4; i++) {
      ahf[i] = *(const bf16x8*)(pah[i] + ko);
      alf[i] = *(const bf16x8*)(pal[i] + ko);
    }
#pragma unroll
    for (int s = 0; s < 3; s++) {
      bhf[s] = *(const bf16x8*)(pbh[s] + ko);
      blf[s] = *(const bf16x8*)(pbl[s] + ko);
    }
#pragma unroll
    for (int i = 0; i < 4; i++) {
#pragma unroll
      for (int s = 0; s < 3; s++) {
        acc[i][s] = __builtin_amdgcn_mfma_f32_16x16x32_bf16(ahf[i], bhf[s], acc[i][s], 0, 0, 0);
        acc[i][s] = __builtin_amdgcn_mfma_f32_16x16x32_bf16(alf[i], bhf[s], acc[i][s], 0, 0, 0);
        acc[i][s] = __builtin_amdgcn_mfma_f32_16x16x32_bf16(ahf[i], blf[s], acc[i][s], 0, 0, 0);
      }
    }
  }

  float avg = *avg_ptr;
  int col = w * 16 + l15;
  float be0 = beff[col], be1 = beff[64 + col], be2 = beff[128 + col];
  float bi = bias[col];
  float ss = 0.f, sq = 0.f;
#pragma unroll
  for (int i = 0; i < 4; i++) {
#pragma unroll
    for (int r = 0; r < 4; r++) {
      int n = n0 + i * 16 + quad * 4 + r;
      if (n < N_NODES) {
        float ld = log_deg[n];
        float amp = ld / avg, att = avg / ld;
        float v = (acc[i][0][r] + be0) + amp * (acc[i][1][r] + be1)
                + att * (acc[i][2][r] + be2) + bi;
        h[(size_t)n * 64 + col] = v;
        ss += v; sq = fmaf(v, v, sq);
      }
    }
  }
  // reduce over quads (same col every 16 lanes)
  ss += __shfl_xor(ss, 16, 64); ss += __shfl_xor(ss, 32, 64);
  sq += __shfl_xor(sq, 16, 64); sq += __shfl_xor(sq, 32, 64);
  if (quad == 0) {
    atomicAdd(&bnacc[col], (double)ss);
    atomicAdd(&bnacc[64 + col], (double)sq);
  }
}

// ===================== BatchNorm finalize + apply =====================

__global__ void bn_finalize_kernel(const double* __restrict__ accS,
                                   const double* __restrict__ accQ,
                                   const float* __restrict__ g,
                                   float* __restrict__ muf, float* __restrict__ scf)
{
  int j = threadIdx.x;  // 64 threads
  double mu = accS[j] / (double)N_NODES;
  double var = accQ[j] / (double)N_NODES - mu * mu;
  double rstd = 1.0 / sqrt(var + 1e-5);
  muf[j] = (float)mu;
  scf[j] = (float)(rstd * (double)g[j]);
}

__global__ __launch_bounds__(256) void apply_kernel(
    const float* __restrict__ h, const float* __restrict__ muf,
    const float* __restrict__ scf, const float* __restrict__ bnb,
    float* __restrict__ x)
{
  int i4 = blockIdx.x * 256 + threadIdx.x;   // float4 index, exact grid
  const float4* h4 = (const float4*)h;
  float4* x4 = (float4*)x;
  int c4 = i4 & 15;
  float4 hv = h4[i4], xv = x4[i4];
  float4 mu = ((const float4*)muf)[c4];
  float4 sc = ((const float4*)scf)[c4];
  float4 bb = ((const float4*)bnb)[c4];
  float4 r;
  r.x = fmaxf((hv.x - mu.x) * sc.x + bb.x, 0.f) + xv.x;
  r.y = fmaxf((hv.y - mu.y) * sc.y + bb.y, 0.f) + xv.y;
  r.z = fmaxf((hv.z - mu.z) * sc.z + bb.z, 0.f) + xv.z;
  r.w = fmaxf((hv.w - mu.w) * sc.w + bb.w, 0.f) + xv.w;
  x4[i4] = r;
}

// ===================== pooling + head =====================

__global__ __launch_bounds__(256) void pool_kernel(
    const float* __restrict__ x, const int* __restrict__ batch,
    float* __restrict__ gsum)
{
  int tid = threadIdx.x;
  int j = tid & 63, ri = tid >> 6;
  float acc = 0.f; int cur = -1;
  for (int k = 0; k < 16; k++) {
    int n = blockIdx.x * 64 + k * 4 + ri;
    if (n < N_NODES) {
      int b = batch[n];
      if (b != cur) {
        if (cur >= 0) atomicAdd(&gsum[cur * 64 + j], acc);
        cur = b; acc = 0.f;
      }
      acc += x[(size_t)n * 64 + j];
    }
  }
  if (cur >= 0) atomicAdd(&gsum[cur * 64 + j], acc);
}

__global__ void fc_kernel(const float* __restrict__ gsum, const int* __restrict__ gcnt,
                          const float* __restrict__ w1, const float* __restrict__ b1,
                          const float* __restrict__ w2, const float* __restrict__ b2,
                          const float* __restrict__ w3, const float* __restrict__ b3,
                          float* __restrict__ out)
{
  int g = threadIdx.x;  // 64 threads, one per graph
  float cnt = fmaxf((float)gcnt[g], 1.0f);
  float gv[64];
#pragma unroll
  for (int j = 0; j < 64; j++) gv[j] = gsum[g * 64 + j] / cnt;
  float a1[32];
#pragma unroll
  for (int o = 0; o < 32; o++) {
    float s = b1[o];
#pragma unroll
    for (int j = 0; j < 64; j++) s = fmaf(gv[j], w1[j * 32 + o], s);
    a1[o] = fmaxf(s, 0.f);
  }
  float a2[16];
#pragma unroll
  for (int o = 0; o < 16; o++) {
    float s = b2[o];
#pragma unroll
    for (int j = 0; j < 32; j++) s = fmaf(a1[j], w2[j * 16 + o], s);
    a2[o] = fmaxf(s, 0.f);
  }
#pragma unroll
  for (int o = 0; o < 10; o++) {
    float s = b3[o];
#pragma unroll
    for (int j = 0; j < 16; j++) s = fmaf(a2[j], w3[j * 10 + o], s);
    out[g * 10 + o] = s;
  }
}

// ===================== launch =====================

extern "C" void kernel_launch(void* const* d_in, const int* in_sizes, int n_in,
                              void* d_out, int out_size, void* d_ws, size_t ws_size,
                              hipStream_t stream)
{
  (void)in_sizes; (void)n_in; (void)out_size; (void)ws_size;
  const float* xin    = (const float*)d_in[0];
  const int*   ei     = (const int*)d_in[1];
  const int*   batch  = (const int*)d_in[2];
  const float* eattr  = (const float*)d_in[3];
  const float* node_w = (const float*)d_in[4];
  const float* node_b = (const float*)d_in[5];
  const float* edge_w = (const float*)d_in[6];
  const float* edge_b = (const float*)d_in[7];
  const float* conv_w = (const float*)d_in[8];
  const float* conv_b = (const float*)d_in[9];
  const float* bn_g   = (const float*)d_in[10];
  const float* bn_b   = (const float*)d_in[11];
  const float* fc1_w  = (const float*)d_in[12];
  const float* fc1_b  = (const float*)d_in[13];
  const float* fc2_w  = (const float*)d_in[14];
  const float* fc2_b  = (const float*)d_in[15];
  const float* fc3_w  = (const float*)d_in[16];
  const float* fc3_b  = (const float*)d_in[17];
  float* out = (float*)d_out;
  const int* srcp = ei;
  const int* dstp = ei + N_EDGES;

  char* p = (char*)d_ws;
  auto alloc = [&](size_t b) { char* r = p; p += (b + 255) & ~(size_t)255; return (void*)r; };
  float*  x       = (float*)alloc((size_t)N_NODES * 64 * 4);
  float*  h       = (float*)alloc((size_t)N_NODES * 64 * 4);
  unsigned short* agg_h = (unsigned short*)alloc((size_t)N_NODES * KEFF * 2);
  unsigned short* agg_l = (unsigned short*)alloc((size_t)N_NODES * KEFF * 2);
  unsigned short* wh    = (unsigned short*)alloc((size_t)3 * 192 * KEFF * 2);
  unsigned short* wl    = (unsigned short*)alloc((size_t)3 * 192 * KEFF * 2);
  int*    srcs    = (int*)alloc((size_t)N_EDGES * 4);
  int*    eids    = (int*)alloc((size_t)N_EDGES * 4);
  float*  beff    = (float*)alloc((size_t)3 * 3 * 64 * 4);
  int*    row_ptr = (int*)alloc((N_NODES + 1) * 4);
  int*    cursor  = (int*)alloc((size_t)N_NODES * 4);
  int*    cnt     = (int*)alloc((size_t)N_NODES * 4);
  float*  log_deg = (float*)alloc((size_t)N_NODES * 4);
  int*    bsum    = (int*)alloc(256 * 4);
  int*    boff    = (int*)alloc(256 * 4);
  double* avgacc  = (double*)alloc(256);
  float*  avgf    = (float*)alloc(256);
  double* bnacc   = (double*)alloc(3 * 128 * 8);
  float*  muf     = (float*)alloc(256);
  float*  scf     = (float*)alloc(256);
  float*  gsum    = (float*)alloc((size_t)NGRAPH * 64 * 4);
  int*    gcnt    = (int*)alloc((size_t)NGRAPH * 4);

  hipMemsetAsync(cnt, 0, (size_t)N_NODES * 4, stream);
  hipMemsetAsync(avgacc, 0, 8, stream);
  hipMemsetAsync(gsum, 0, (size_t)NGRAPH * 64 * 4, stream);
  hipMemsetAsync(bnacc, 0, 3 * 128 * 8, stream);

  node_enc_kernel<<<12500, 256, 0, stream>>>(xin, node_w, node_b, x);
  count_kernel<<<3125, 256, 0, stream>>>(dstp, cnt);
  scan_a_kernel<<<196, 256, 0, stream>>>(cnt, bsum);
  scan_b_kernel<<<1, 256, 0, stream>>>(bsum, boff);
  scan_c_kernel<<<196, 256, 0, stream>>>(cnt, boff, row_ptr);
  hipMemcpyAsync(cursor, row_ptr, (size_t)N_NODES * 4, hipMemcpyDeviceToDevice, stream);
  fill_kernel<<<3125, 256, 0, stream>>>(srcp, dstp, cursor, srcs, eids);
  deg_log_kernel<<<196, 256, 0, stream>>>(cnt, log_deg, avgacc);
  finalize_avg_kernel<<<1, 1, 0, stream>>>(avgacc, avgf);
  gbound_kernel<<<1, 64, 0, stream>>>(batch, gcnt);
  wprep_kernel<<<1296, 256, 0, stream>>>(conv_w, wh, wl);
  bprep_kernel<<<3, 192, 0, stream>>>(conv_w, beff);

  agg_e_kernel<<<12500, 256, 0, stream>>>(eattr, edge_w, edge_b, row_ptr,
                                          eids, agg_h, agg_l);

  for (int l = 0; l < 3; l++) {
    agg_x_kernel<<<12500, 256, 0, stream>>>(x, srcs, row_ptr, agg_h, agg_l);
    gemm_kernel<<<782, 256, 0, stream>>>(agg_h, agg_l,
                                         wh + (size_t)l * 192 * KEFF,
                                         wl + (size_t)l * 192 * KEFF,
                                         beff + l * 192, conv_b + l * 64,
                                         log_deg, avgf, h, bnacc + l * 128);
    bn_finalize_kernel<<<1, 64, 0, stream>>>(bnacc + l * 128, bnacc + l * 128 + 64,
                                             bn_g + l * 64, muf, scf);
    apply_kernel<<<3125, 256, 0, stream>>>(h, muf, scf, bn_b + l * 64, x);
  }

  pool_kernel<<<782, 256, 0, stream>>>(x, batch, gsum);
  fc_kernel<<<1, 64, 0, stream>>>(gsum, gcnt, fc1_w, fc1_b, fc2_w, fc2_b,
                                  fc3_w, fc3_b, out);
}

// Round 8
// 759.891 us; speedup vs baseline: 1.1988x; 1.1988x over previous
//
#include <hip/hip_runtime.h>
#include <math.h>

#define N_NODES 50000
#define N_EDGES 800000
#define NGRAPH  64
#define KEFF    576      // compressed agg width (768->576 via x_dst folding)
#define NGROUP  3128     // 782 M-tiles * 4 groups of 16 rows (50048 rows, 48 pad)
#define GSTRIDE 9216     // shorts per group = 72 kc * 128

typedef short bf16x8 __attribute__((ext_vector_type(8)));
typedef float f32x4  __attribute__((ext_vector_type(4)));

__device__ inline unsigned short f2bf_rne(float f) {
  unsigned u = __float_as_uint(f);
  unsigned r = u + 0x7FFFu + ((u >> 16) & 1u);
  return (unsigned short)(r >> 16);
}
__device__ inline float bf2f(unsigned short h) {
  return __uint_as_float(((unsigned)h) << 16);
}

// ===================== setup kernels =====================

__global__ __launch_bounds__(256) void node_enc_kernel(
    const float* __restrict__ xin, const float* __restrict__ nw,
    const float* __restrict__ nb, float* __restrict__ x)
{
  __shared__ float xs[256];
  int tid = threadIdx.x;
  int base = blockIdx.x * 256;          // 4 nodes per block
  xs[tid] = xin[base + tid];
  __syncthreads();
  int r = tid >> 6, j = tid & 63;
  float acc = nb[j];
#pragma unroll
  for (int t = 0; t < 64; t++) acc = fmaf(xs[r * 64 + t], nw[t * 64 + j], acc);
  x[base + tid] = acc;
}

__global__ void count_kernel(const int* __restrict__ dst, int* __restrict__ cnt)
{
  int e = blockIdx.x * 256 + threadIdx.x;   // grid exactly covers E
  atomicAdd(&cnt[dst[e]], 1);
}

__global__ __launch_bounds__(256) void scan_a_kernel(
    const int* __restrict__ cnt, int* __restrict__ bsum)
{
  __shared__ int s[256];
  int i = blockIdx.x * 256 + threadIdx.x;
  s[threadIdx.x] = (i < N_NODES) ? cnt[i] : 0;
  __syncthreads();
  for (int off = 128; off > 0; off >>= 1) {
    if (threadIdx.x < off) s[threadIdx.x] += s[threadIdx.x + off];
    __syncthreads();
  }
  if (threadIdx.x == 0) bsum[blockIdx.x] = s[0];
}

__global__ __launch_bounds__(256) void scan_b_kernel(
    const int* __restrict__ bsum, int* __restrict__ boff)
{
  __shared__ int s[256];
  int tid = threadIdx.x;
  int v = (tid < 196) ? bsum[tid] : 0;
  s[tid] = v;
  __syncthreads();
  for (int off = 1; off < 256; off <<= 1) {
    int t = (tid >= off) ? s[tid - off] : 0;
    __syncthreads();
    s[tid] += t;
    __syncthreads();
  }
  boff[tid] = s[tid] - v;   // exclusive prefix of block sums
}

__global__ __launch_bounds__(256) void scan_c_kernel(
    const int* __restrict__ cnt, const int* __restrict__ boff,
    int* __restrict__ row_ptr)
{
  __shared__ int s[256];
  int tid = threadIdx.x;
  int i = blockIdx.x * 256 + tid;
  int v = (i < N_NODES) ? cnt[i] : 0;
  s[tid] = v;
  __syncthreads();
  for (int off = 1; off < 256; off <<= 1) {
    int t = (tid >= off) ? s[tid - off] : 0;
    __syncthreads();
    s[tid] += t;
    __syncthreads();
  }
  int incl = s[tid];
  int base = boff[blockIdx.x];
  if (i < N_NODES) row_ptr[i] = base + incl - v;
  if (i == N_NODES - 1) row_ptr[N_NODES] = base + incl;
}

__global__ void fill_kernel(const int* __restrict__ src, const int* __restrict__ dst,
                            int* __restrict__ cursor, int* __restrict__ srcs,
                            int* __restrict__ eids)
{
  int e = blockIdx.x * 256 + threadIdx.x;
  int d = dst[e];
  int pos = atomicAdd(&cursor[d], 1);
  srcs[pos] = src[e];
  eids[pos] = e;
}

__global__ __launch_bounds__(256) void deg_log_kernel(
    const int* __restrict__ cnt, float* __restrict__ log_deg,
    double* __restrict__ avgacc)
{
  __shared__ double sb[256];
  int i = blockIdx.x * 256 + threadIdx.x;
  double c = 0.0;
  if (i < N_NODES) {
    int d = cnt[i];
    int dc = d > 0 ? d : 1;
    log_deg[i] = logf((float)dc + 1.0f);         // log(degc + 1)
    c = (double)logf((float)d + 1.0f);           // avg uses raw deg
  }
  sb[threadIdx.x] = c;
  __syncthreads();
  for (int off = 128; off > 0; off >>= 1) {
    if (threadIdx.x < off) sb[threadIdx.x] += sb[threadIdx.x + off];
    __syncthreads();
  }
  if (threadIdx.x == 0) atomicAdd(avgacc, sb[0]);
}

__global__ void finalize_avg_kernel(const double* __restrict__ avgacc,
                                    float* __restrict__ avgf)
{
  *avgf = (float)(*avgacc / (double)N_NODES);
}

// graph node counts from sorted batch via binary search
__global__ void gbound_kernel(const int* __restrict__ batch, int* __restrict__ gcnt)
{
  __shared__ int sb[65];
  int g = threadIdx.x;  // 64 threads
  int lo = 0, hi = N_NODES;
  while (lo < hi) { int mid = (lo + hi) >> 1; if (batch[mid] < g) lo = mid + 1; else hi = mid; }
  sb[g] = lo;
  if (g == 0) sb[64] = N_NODES;
  __syncthreads();
  gcnt[g] = sb[g + 1] - sb[g];
}

// ===================== weight prep: fold + bf16 hi/lo, MFMA-swizzled ========
// Out layout: [l][colgroup cg=c/16][kc=k/8][c15=c%16][ko=k%8] (8 bf16 = 16B
// per (cg,kc,c15)); a B-fragment load is then lane-contiguous (coalesced).

__global__ __launch_bounds__(256) void wprep_kernel(
    const float* __restrict__ conv_w, unsigned short* __restrict__ wh,
    unsigned short* __restrict__ wl)
{
  int idx = blockIdx.x * 256 + threadIdx.x;   // 3*192*576 = 331776 = 1296*256
  int k = idx % 576;
  int c = (idx / 576) % 192;
  int l = idx / (576 * 192);
  int s = c >> 6, j = c & 63;
  const float* CW = conv_w + (size_t)l * 2304 * 64;
  float v;
  if (k < 64) {
    int base = s * 768 + k;
    v = CW[base * 64 + j] + CW[(base + 192) * 64 + j] + CW[(base + 384) * 64 + j];
  } else {
    const int srcseg[8] = {1, 2, 4, 5, 7, 8, 10, 11};
    int q = (k >> 6) - 1;
    int t = k & 63;
    v = CW[(s * 768 + srcseg[q] * 64 + t) * 64 + j];
  }
  unsigned short hh = f2bf_rne(v);
  size_t o = (((size_t)l * 12 + (c >> 4)) * 72 + (k >> 3)) * 128 + (c & 15) * 8 + (k & 7);
  wh[o] = hh;
  wl[o] = f2bf_rne(v - bf2f(hh));
}

__global__ void bprep_kernel(const float* __restrict__ conv_w, float* __restrict__ beff)
{
  int l = blockIdx.x;                 // 3 blocks x 192 threads
  int s = threadIdx.x >> 6, j = threadIdx.x & 63;
  const float* CW = conv_w + (size_t)l * 2304 * 64 + (size_t)(s * 768 + 576) * 64;
  float sum = 0.f;
#pragma unroll
  for (int t = 0; t < 64; t++) sum += CW[t * 64 + j];
  beff[(l * 3 + s) * 64 + j] = sum * 0.0031622776601683794f;   // sqrt(1e-5)
}

// agg store in MFMA-swizzled A layout: group g=n/16, r=n%16;
// feature f in segment seg -> k = seg*64+f: offset (seg*8+f/8)*128 + r*8 + f%8.
#define AGG_STORE(bh, bl, seg, f, val) { \
  float _v = (val); unsigned short _h = f2bf_rne(_v); \
  int _o = ((seg) * 8 + ((f) >> 3)) * 128 + ((f) & 7); \
  (bh)[_o] = _h; (bl)[_o] = f2bf_rne(_v - bf2f(_h)); }

// ===================== e-segment aggregation (layer-invariant, once) ========

__global__ __launch_bounds__(256) void agg_e_kernel(
    const float* __restrict__ eattr, const float* __restrict__ edge_w,
    const float* __restrict__ edge_b, const int* __restrict__ row_ptr,
    const int* __restrict__ eids,
    unsigned short* __restrict__ agg_h, unsigned short* __restrict__ agg_l)
{
  int lane = threadIdx.x & 63;
  int quad = lane >> 4, a16 = lane & 15;
  int n = blockIdx.x * 4 + (threadIdx.x >> 6);
  if (n >= N_NODES) return;
  float ew[16];
#pragma unroll
  for (int t = 0; t < 16; t++) ew[t] = edge_w[t * 64 + lane];
  float eb = edge_b[lane];
  int s0 = row_ptr[n], s1 = row_ptr[n + 1];
  float se = 0.f, qe = 0.f, mxe = -3.4e38f, mne = 3.4e38f;

  for (int j = s0; j < s1; j += 4) {
    int idx = j + quad;
    float av = 0.f;
    if (idx < s1) av = eattr[(size_t)eids[idx] * 16 + a16];
    unsigned au = __float_as_uint(av);
    float ea[4];
#pragma unroll
    for (int q = 0; q < 4; q++) {
      float c0 = eb, c1 = 0.f;
#pragma unroll
      for (int t = 0; t < 8; t++) {
        c0 = fmaf(__uint_as_float(__builtin_amdgcn_readlane(au, q * 16 + t)), ew[t], c0);
        c1 = fmaf(__uint_as_float(__builtin_amdgcn_readlane(au, q * 16 + 8 + t)), ew[8 + t], c1);
      }
      ea[q] = c0 + c1;
    }
    int rem = s1 - j;   // wave-uniform
#pragma unroll
    for (int q = 0; q < 4; q++) {
      if (q < rem) {
        se += ea[q]; qe = fmaf(ea[q], ea[q], qe);
        mxe = fmaxf(mxe, ea[q]); mne = fminf(mne, ea[q]);
      }
    }
  }

  int deg = s1 - s0;
  float inv = 1.0f / fmaxf((float)deg, 1.0f);
  bool has = deg > 0;
  float m_e = se * inv, ms_e = qe * inv;
  float sd_e = sqrtf(fmaxf(ms_e - m_e * m_e, 0.f) + 1e-5f);
  float mx_e = has ? mxe : 0.f, mn_e = has ? mne : 0.f;

  unsigned short* bh = agg_h + (size_t)(n >> 4) * GSTRIDE + (n & 15) * 8;
  unsigned short* bl = agg_l + (size_t)(n >> 4) * GSTRIDE + (n & 15) * 8;
  AGG_STORE(bh, bl, 2, lane, m_e);
  AGG_STORE(bh, bl, 4, lane, mn_e);
  AGG_STORE(bh, bl, 6, lane, mx_e);
  AGG_STORE(bh, bl, 8, lane, sd_e);
}

// ===================== per-layer x-segment aggregation =====================
// x8 unroll: 8 gathers in flight, 4 rotating accumulator chains.

__global__ __launch_bounds__(256) void agg_x_kernel(
    const float* __restrict__ x, const int* __restrict__ srcs,
    const int* __restrict__ row_ptr,
    unsigned short* __restrict__ agg_h, unsigned short* __restrict__ agg_l)
{
  int lane = threadIdx.x & 63;
  int n = blockIdx.x * 4 + (threadIdx.x >> 6);
  if (n >= N_NODES) return;
  float xd = x[(size_t)n * 64 + lane];
  int s0 = row_ptr[n], s1 = row_ptr[n + 1];
  float sA = 0.f, sB = 0.f, sC = 0.f, sD = 0.f;
  float qA = 0.f, qB = 0.f, qC = 0.f, qD = 0.f;
  float mx0 = -3.4e38f, mx1 = -3.4e38f, mn0 = 3.4e38f, mn1 = 3.4e38f;
  int j = s0;
  for (; j + 7 < s1; j += 8) {
    int e0 = srcs[j],     e1 = srcs[j + 1], e2 = srcs[j + 2], e3 = srcs[j + 3];
    int e4 = srcs[j + 4], e5 = srcs[j + 5], e6 = srcs[j + 6], e7 = srcs[j + 7];
    float x0 = x[(size_t)e0 * 64 + lane];
    float x1 = x[(size_t)e1 * 64 + lane];
    float x2 = x[(size_t)e2 * 64 + lane];
    float x3 = x[(size_t)e3 * 64 + lane];
    float x4 = x[(size_t)e4 * 64 + lane];
    float x5 = x[(size_t)e5 * 64 + lane];
    float x6 = x[(size_t)e6 * 64 + lane];
    float x7 = x[(size_t)e7 * 64 + lane];
    sA += x0; sB += x1; sC += x2; sD += x3;
    sA += x4; sB += x5; sC += x6; sD += x7;
    qA = fmaf(x0, x0, qA); qB = fmaf(x1, x1, qB);
    qC = fmaf(x2, x2, qC); qD = fmaf(x3, x3, qD);
    qA = fmaf(x4, x4, qA); qB = fmaf(x5, x5, qB);
    qC = fmaf(x6, x6, qC); qD = fmaf(x7, x7, qD);
    mx0 = fmaxf(mx0, fmaxf(fmaxf(x0, x1), fmaxf(x2, x3)));
    mx1 = fmaxf(mx1, fmaxf(fmaxf(x4, x5), fmaxf(x6, x7)));
    mn0 = fminf(mn0, fminf(fminf(x0, x1), fminf(x2, x3)));
    mn1 = fminf(mn1, fminf(fminf(x4, x5), fminf(x6, x7)));
  }
  for (; j + 3 < s1; j += 4) {
    int e0 = srcs[j], e1 = srcs[j + 1], e2 = srcs[j + 2], e3 = srcs[j + 3];
    float x0 = x[(size_t)e0 * 64 + lane];
    float x1 = x[(size_t)e1 * 64 + lane];
    float x2 = x[(size_t)e2 * 64 + lane];
    float x3 = x[(size_t)e3 * 64 + lane];
    sA += x0; sB += x1; sC += x2; sD += x3;
    qA = fmaf(x0, x0, qA); qB = fmaf(x1, x1, qB);
    qC = fmaf(x2, x2, qC); qD = fmaf(x3, x3, qD);
    mx0 = fmaxf(mx0, fmaxf(x0, x1)); mx1 = fmaxf(mx1, fmaxf(x2, x3));
    mn0 = fminf(mn0, fminf(x0, x1)); mn1 = fminf(mn1, fminf(x2, x3));
  }
  for (; j < s1; j++) {
    float xa = x[(size_t)srcs[j] * 64 + lane];
    sA += xa; qA = fmaf(xa, xa, qA);
    mx0 = fmaxf(mx0, xa); mn0 = fminf(mn0, xa);
  }
  float sx = (sA + sB) + (sC + sD);
  float qx = (qA + qB) + (qC + qD);
  float mxx = fmaxf(mx0, mx1), mnx = fminf(mn0, mn1);

  int deg = s1 - s0;
  float inv = 1.0f / fmaxf((float)deg, 1.0f);
  bool has = deg > 0;
  float m_s = sx * inv, ms_s = qx * inv;
  float sd_s = sqrtf(fmaxf(ms_s - m_s * m_s, 0.f) + 1e-5f);
  float mx_s = has ? mxx : 0.f, mn_s = has ? mnx : 0.f;

  unsigned short* bh = agg_h + (size_t)(n >> 4) * GSTRIDE + (n & 15) * 8;
  unsigned short* bl = agg_l + (size_t)(n >> 4) * GSTRIDE + (n & 15) * 8;
  AGG_STORE(bh, bl, 0, lane, has ? xd : 0.f);
  AGG_STORE(bh, bl, 1, lane, m_s);
  AGG_STORE(bh, bl, 3, lane, mn_s);
  AGG_STORE(bh, bl, 5, lane, mx_s);
  AGG_STORE(bh, bl, 7, lane, sd_s);
}

// ===================== MFMA GEMM v4: swizzled, LDS-free, barrier-free ======
// A and B stored in MFMA fragment order -> every fragment load is a 1KB
// coalesced wave read. No LDS, no __syncthreads. 256 thr / 4 waves, M=64
// (4 row-groups of 16), N=192; wave w owns cols {s*64 + w*16 + l15}.

__global__ __launch_bounds__(256, 4) void gemm_kernel(
    const unsigned short* __restrict__ Ah, const unsigned short* __restrict__ Al,
    const unsigned short* __restrict__ Wh, const unsigned short* __restrict__ Wl,
    const float* __restrict__ beff, const float* __restrict__ bias,
    const float* __restrict__ log_deg, const float* __restrict__ avg_ptr,
    float* __restrict__ h, double* __restrict__ bnacc)
{
  int tid = threadIdx.x;
  int lane = tid & 63, w = tid >> 6;
  int quad = lane >> 4, l15 = lane & 15;
  int n0 = blockIdx.x * 64;

  // A group base pointers (+ lane row offset)
  const unsigned short* pah[4];
  const unsigned short* pal[4];
#pragma unroll
  for (int i = 0; i < 4; i++) {
    size_t gb = (size_t)(blockIdx.x * 4 + i) * GSTRIDE + l15 * 8;
    pah[i] = Ah + gb;
    pal[i] = Al + gb;
  }
  // B colgroup base pointers: cg = s*4 + w
  const unsigned short* pbh[3];
  const unsigned short* pbl[3];
#pragma unroll
  for (int s = 0; s < 3; s++) {
    size_t cb = (size_t)(s * 4 + w) * 72 * 128 + l15 * 8;
    pbh[s] = Wh + cb;
    pbl[s] = Wl + cb;
  }

  f32x4 acc[4][3] = {};

#pragma unroll 2
  for (int k0 = 0; k0 < KEFF; k0 += 32) {
    int koff = ((k0 >> 3) + quad) * 128;
    bf16x8 ahf[4], alf[4], bhf[3], blf[3];
#pragma unroll
    for (int i = 0; i < 4; i++) {
      ahf[i] = *(const bf16x8*)(pah[i] + koff);
      alf[i] = *(const bf16x8*)(pal[i] + koff);
    }
#pragma unroll
    for (int s = 0; s < 3; s++) {
      bhf[s] = *(const bf16x8*)(pbh[s] + koff);
      blf[s] = *(const bf16x8*)(pbl[s] + koff);
    }
#pragma unroll
    for (int i = 0; i < 4; i++) {
#pragma unroll
      for (int s = 0; s < 3; s++) {
        acc[i][s] = __builtin_amdgcn_mfma_f32_16x16x32_bf16(ahf[i], bhf[s], acc[i][s], 0, 0, 0);
        acc[i][s] = __builtin_amdgcn_mfma_f32_16x16x32_bf16(alf[i], bhf[s], acc[i][s], 0, 0, 0);
        acc[i][s] = __builtin_amdgcn_mfma_f32_16x16x32_bf16(ahf[i], blf[s], acc[i][s], 0, 0, 0);
      }
    }
  }

  float avg = *avg_ptr;
  int col = w * 16 + l15;
  float be0 = beff[col], be1 = beff[64 + col], be2 = beff[128 + col];
  float bi = bias[col];
  float ss = 0.f, sq = 0.f;
#pragma unroll
  for (int i = 0; i < 4; i++) {
#pragma unroll
    for (int r = 0; r < 4; r++) {
      int n = n0 + i * 16 + quad * 4 + r;
      if (n < N_NODES) {
        float ld = log_deg[n];
        float amp = ld / avg, att = avg / ld;
        float v = (acc[i][0][r] + be0) + amp * (acc[i][1][r] + be1)
                + att * (acc[i][2][r] + be2) + bi;
        h[(size_t)n * 64 + col] = v;
        ss += v; sq = fmaf(v, v, sq);
      }
    }
  }
  // reduce over quads (same col every 16 lanes)
  ss += __shfl_xor(ss, 16, 64); ss += __shfl_xor(ss, 32, 64);
  sq += __shfl_xor(sq, 16, 64); sq += __shfl_xor(sq, 32, 64);
  if (quad == 0) {
    atomicAdd(&bnacc[col], (double)ss);
    atomicAdd(&bnacc[64 + col], (double)sq);
  }
}

// ===================== BatchNorm finalize + apply =====================

__global__ void bn_finalize_kernel(const double* __restrict__ accS,
                                   const double* __restrict__ accQ,
                                   const float* __restrict__ g,
                                   float* __restrict__ muf, float* __restrict__ scf)
{
  int j = threadIdx.x;  // 64 threads
  double mu = accS[j] / (double)N_NODES;
  double var = accQ[j] / (double)N_NODES - mu * mu;
  double rstd = 1.0 / sqrt(var + 1e-5);
  muf[j] = (float)mu;
  scf[j] = (float)(rstd * (double)g[j]);
}

__global__ __launch_bounds__(256) void apply_kernel(
    const float* __restrict__ h, const float* __restrict__ muf,
    const float* __restrict__ scf, const float* __restrict__ bnb,
    float* __restrict__ x)
{
  int i4 = blockIdx.x * 256 + threadIdx.x;   // float4 index, exact grid
  const float4* h4 = (const float4*)h;
  float4* x4 = (float4*)x;
  int c4 = i4 & 15;
  float4 hv = h4[i4], xv = x4[i4];
  float4 mu = ((const float4*)muf)[c4];
  float4 sc = ((const float4*)scf)[c4];
  float4 bb = ((const float4*)bnb)[c4];
  float4 r;
  r.x = fmaxf((hv.x - mu.x) * sc.x + bb.x, 0.f) + xv.x;
  r.y = fmaxf((hv.y - mu.y) * sc.y + bb.y, 0.f) + xv.y;
  r.z = fmaxf((hv.z - mu.z) * sc.z + bb.z, 0.f) + xv.z;
  r.w = fmaxf((hv.w - mu.w) * sc.w + bb.w, 0.f) + xv.w;
  x4[i4] = r;
}

// ===================== pooling + head =====================

__global__ __launch_bounds__(256) void pool_kernel(
    const float* __restrict__ x, const int* __restrict__ batch,
    float* __restrict__ gsum)
{
  int tid = threadIdx.x;
  int j = tid & 63, ri = tid >> 6;
  float acc = 0.f; int cur = -1;
  for (int k = 0; k < 16; k++) {
    int n = blockIdx.x * 64 + k * 4 + ri;
    if (n < N_NODES) {
      int b = batch[n];
      if (b != cur) {
        if (cur >= 0) atomicAdd(&gsum[cur * 64 + j], acc);
        cur = b; acc = 0.f;
      }
      acc += x[(size_t)n * 64 + j];
    }
  }
  if (cur >= 0) atomicAdd(&gsum[cur * 64 + j], acc);
}

__global__ void fc_kernel(const float* __restrict__ gsum, const int* __restrict__ gcnt,
                          const float* __restrict__ w1, const float* __restrict__ b1,
                          const float* __restrict__ w2, const float* __restrict__ b2,
                          const float* __restrict__ w3, const float* __restrict__ b3,
                          float* __restrict__ out)
{
  int g = threadIdx.x;  // 64 threads, one per graph
  float cnt = fmaxf((float)gcnt[g], 1.0f);
  float gv[64];
#pragma unroll
  for (int j = 0; j < 64; j++) gv[j] = gsum[g * 64 + j] / cnt;
  float a1[32];
#pragma unroll
  for (int o = 0; o < 32; o++) {
    float s = b1[o];
#pragma unroll
    for (int j = 0; j < 64; j++) s = fmaf(gv[j], w1[j * 32 + o], s);
    a1[o] = fmaxf(s, 0.f);
  }
  float a2[16];
#pragma unroll
  for (int o = 0; o < 16; o++) {
    float s = b2[o];
#pragma unroll
    for (int j = 0; j < 32; j++) s = fmaf(a1[j], w2[j * 16 + o], s);
    a2[o] = fmaxf(s, 0.f);
  }
#pragma unroll
  for (int o = 0; o < 10; o++) {
    float s = b3[o];
#pragma unroll
    for (int j = 0; j < 16; j++) s = fmaf(a2[j], w3[j * 10 + o], s);
    out[g * 10 + o] = s;
  }
}

// ===================== launch =====================

extern "C" void kernel_launch(void* const* d_in, const int* in_sizes, int n_in,
                              void* d_out, int out_size, void* d_ws, size_t ws_size,
                              hipStream_t stream)
{
  (void)in_sizes; (void)n_in; (void)out_size; (void)ws_size;
  const float* xin    = (const float*)d_in[0];
  const int*   ei     = (const int*)d_in[1];
  const int*   batch  = (const int*)d_in[2];
  const float* eattr  = (const float*)d_in[3];
  const float* node_w = (const float*)d_in[4];
  const float* node_b = (const float*)d_in[5];
  const float* edge_w = (const float*)d_in[6];
  const float* edge_b = (const float*)d_in[7];
  const float* conv_w = (const float*)d_in[8];
  const float* conv_b = (const float*)d_in[9];
  const float* bn_g   = (const float*)d_in[10];
  const float* bn_b   = (const float*)d_in[11];
  const float* fc1_w  = (const float*)d_in[12];
  const float* fc1_b  = (const float*)d_in[13];
  const float* fc2_w  = (const float*)d_in[14];
  const float* fc2_b  = (const float*)d_in[15];
  const float* fc3_w  = (const float*)d_in[16];
  const float* fc3_b  = (const float*)d_in[17];
  float* out = (float*)d_out;
  const int* srcp = ei;
  const int* dstp = ei + N_EDGES;

  char* p = (char*)d_ws;
  auto alloc = [&](size_t b) { char* r = p; p += (b + 255) & ~(size_t)255; return (void*)r; };
  float*  x       = (float*)alloc((size_t)N_NODES * 64 * 4);
  float*  h       = (float*)alloc((size_t)N_NODES * 64 * 4);
  unsigned short* agg_h = (unsigned short*)alloc((size_t)NGROUP * GSTRIDE * 2);
  unsigned short* agg_l = (unsigned short*)alloc((size_t)NGROUP * GSTRIDE * 2);
  unsigned short* wh    = (unsigned short*)alloc((size_t)3 * 12 * 72 * 128 * 2);
  unsigned short* wl    = (unsigned short*)alloc((size_t)3 * 12 * 72 * 128 * 2);
  int*    srcs    = (int*)alloc((size_t)N_EDGES * 4);
  int*    eids    = (int*)alloc((size_t)N_EDGES * 4);
  float*  beff    = (float*)alloc((size_t)3 * 3 * 64 * 4);
  int*    row_ptr = (int*)alloc((N_NODES + 1) * 4);
  int*    cursor  = (int*)alloc((size_t)N_NODES * 4);
  int*    cnt     = (int*)alloc((size_t)N_NODES * 4);
  float*  log_deg = (float*)alloc((size_t)N_NODES * 4);
  int*    bsum    = (int*)alloc(256 * 4);
  int*    boff    = (int*)alloc(256 * 4);
  double* avgacc  = (double*)alloc(256);
  float*  avgf    = (float*)alloc(256);
  double* bnacc   = (double*)alloc(3 * 128 * 8);
  float*  muf     = (float*)alloc(256);
  float*  scf     = (float*)alloc(256);
  float*  gsum    = (float*)alloc((size_t)NGRAPH * 64 * 4);
  int*    gcnt    = (int*)alloc((size_t)NGRAPH * 4);

  hipMemsetAsync(cnt, 0, (size_t)N_NODES * 4, stream);
  hipMemsetAsync(avgacc, 0, 8, stream);
  hipMemsetAsync(gsum, 0, (size_t)NGRAPH * 64 * 4, stream);
  hipMemsetAsync(bnacc, 0, 3 * 128 * 8, stream);

  node_enc_kernel<<<12500, 256, 0, stream>>>(xin, node_w, node_b, x);
  count_kernel<<<3125, 256, 0, stream>>>(dstp, cnt);
  scan_a_kernel<<<196, 256, 0, stream>>>(cnt, bsum);
  scan_b_kernel<<<1, 256, 0, stream>>>(bsum, boff);
  scan_c_kernel<<<196, 256, 0, stream>>>(cnt, boff, row_ptr);
  hipMemcpyAsync(cursor, row_ptr, (size_t)N_NODES * 4, hipMemcpyDeviceToDevice, stream);
  fill_kernel<<<3125, 256, 0, stream>>>(srcp, dstp, cursor, srcs, eids);
  deg_log_kernel<<<196, 256, 0, stream>>>(cnt, log_deg, avgacc);
  finalize_avg_kernel<<<1, 1, 0, stream>>>(avgacc, avgf);
  gbound_kernel<<<1, 64, 0, stream>>>(batch, gcnt);
  wprep_kernel<<<1296, 256, 0, stream>>>(conv_w, wh, wl);
  bprep_kernel<<<3, 192, 0, stream>>>(conv_w, beff);

  agg_e_kernel<<<12500, 256, 0, stream>>>(eattr, edge_w, edge_b, row_ptr,
                                          eids, agg_h, agg_l);

  for (int l = 0; l < 3; l++) {
    agg_x_kernel<<<12500, 256, 0, stream>>>(x, srcs, row_ptr, agg_h, agg_l);
    gemm_kernel<<<782, 256, 0, stream>>>(agg_h, agg_l,
                                         wh + (size_t)l * 12 * 72 * 128,
                                         wl + (size_t)l * 12 * 72 * 128,
                                         beff + l * 192, conv_b + l * 64,
                                         log_deg, avgf, h, bnacc + l * 128);
    bn_finalize_kernel<<<1, 64, 0, stream>>>(bnacc + l * 128, bnacc + l * 128 + 64,
                                             bn_g + l * 64, muf, scf);
    apply_kernel<<<3125, 256, 0, stream>>>(h, muf, scf, bn_b + l * 64, x);
  }

  pool_kernel<<<782, 256, 0, stream>>>(x, batch, gsum);
  fc_kernel<<<1, 64, 0, stream>>>(gsum, gcnt, fc1_w, fc1_b, fc2_w, fc2_b,
                                  fc3_w, fc3_b, out);
}

// Round 9
// 682.684 us; speedup vs baseline: 1.3344x; 1.1131x over previous
//
#include <hip/hip_runtime.h>
#include <math.h>

#define N_NODES 50000
#define N_EDGES 800000
#define NGRAPH  64
#define KEFF    576   // compressed agg width (768->576 via x_dst folding)

typedef short bf16x8 __attribute__((ext_vector_type(8)));
typedef float f32x4  __attribute__((ext_vector_type(4)));

__device__ inline unsigned short f2bf_rne(float f) {
  unsigned u = __float_as_uint(f);
  unsigned r = u + 0x7FFFu + ((u >> 16) & 1u);
  return (unsigned short)(r >> 16);
}
__device__ inline float bf2f(unsigned short h) {
  return __uint_as_float(((unsigned)h) << 16);
}

// ===================== setup kernels =====================

// one kernel zeroes everything (replaces 4 memset dispatches)
__global__ __launch_bounds__(256) void zero_kernel(
    int* __restrict__ cnt, float* __restrict__ gsum,
    double* __restrict__ bnacc, double* __restrict__ avgacc)
{
  int i = blockIdx.x * 256 + threadIdx.x;   // grid 213 -> 54528
  if (i < N_NODES) { cnt[i] = 0; return; }
  int j = i - N_NODES;
  if (j < NGRAPH * 64) { gsum[j] = 0.f; return; }
  int k = j - NGRAPH * 64;
  if (k < 3 * 128) { bnacc[k] = 0.0; return; }
  if (k == 3 * 128) *avgacc = 0.0;
}

__global__ __launch_bounds__(256) void node_enc_kernel(
    const float* __restrict__ xin, const float* __restrict__ nw,
    const float* __restrict__ nb, float* __restrict__ x)
{
  __shared__ float xs[256];
  int tid = threadIdx.x;
  int base = blockIdx.x * 256;          // 4 nodes per block
  xs[tid] = xin[base + tid];
  __syncthreads();
  int r = tid >> 6, j = tid & 63;
  float acc = nb[j];
#pragma unroll
  for (int t = 0; t < 64; t++) acc = fmaf(xs[r * 64 + t], nw[t * 64 + j], acc);
  x[base + tid] = acc;
}

__global__ void count_kernel(const int* __restrict__ dst, int* __restrict__ cnt)
{
  int e = blockIdx.x * 256 + threadIdx.x;   // grid exactly covers E
  atomicAdd(&cnt[dst[e]], 1);
}

__global__ __launch_bounds__(256) void scan_a_kernel(
    const int* __restrict__ cnt, int* __restrict__ bsum)
{
  __shared__ int s[256];
  int i = blockIdx.x * 256 + threadIdx.x;
  s[threadIdx.x] = (i < N_NODES) ? cnt[i] : 0;
  __syncthreads();
  for (int off = 128; off > 0; off >>= 1) {
    if (threadIdx.x < off) s[threadIdx.x] += s[threadIdx.x + off];
    __syncthreads();
  }
  if (threadIdx.x == 0) bsum[blockIdx.x] = s[0];
}

__global__ __launch_bounds__(256) void scan_b_kernel(
    const int* __restrict__ bsum, int* __restrict__ boff)
{
  __shared__ int s[256];
  int tid = threadIdx.x;
  int v = (tid < 196) ? bsum[tid] : 0;
  s[tid] = v;
  __syncthreads();
  for (int off = 1; off < 256; off <<= 1) {
    int t = (tid >= off) ? s[tid - off] : 0;
    __syncthreads();
    s[tid] += t;
    __syncthreads();
  }
  boff[tid] = s[tid] - v;   // exclusive prefix of block sums
}

__global__ __launch_bounds__(256) void scan_c_kernel(
    const int* __restrict__ cnt, const int* __restrict__ boff,
    int* __restrict__ row_ptr, int* __restrict__ cursor)
{
  __shared__ int s[256];
  int tid = threadIdx.x;
  int i = blockIdx.x * 256 + tid;
  int v = (i < N_NODES) ? cnt[i] : 0;
  s[tid] = v;
  __syncthreads();
  for (int off = 1; off < 256; off <<= 1) {
    int t = (tid >= off) ? s[tid - off] : 0;
    __syncthreads();
    s[tid] += t;
    __syncthreads();
  }
  int incl = s[tid];
  int base = boff[blockIdx.x];
  if (i < N_NODES) { row_ptr[i] = base + incl - v; cursor[i] = base + incl - v; }
  if (i == N_NODES - 1) row_ptr[N_NODES] = base + incl;
}

__global__ void fill_kernel(const int* __restrict__ src, const int* __restrict__ dst,
                            int* __restrict__ cursor, int* __restrict__ srcs,
                            int* __restrict__ eids)
{
  int e = blockIdx.x * 256 + threadIdx.x;
  int d = dst[e];
  int pos = atomicAdd(&cursor[d], 1);
  srcs[pos] = src[e];
  eids[pos] = e;
}

__global__ __launch_bounds__(256) void deg_log_kernel(
    const int* __restrict__ cnt, float* __restrict__ log_deg,
    double* __restrict__ avgacc)
{
  __shared__ double sb[256];
  int i = blockIdx.x * 256 + threadIdx.x;
  double c = 0.0;
  if (i < N_NODES) {
    int d = cnt[i];
    int dc = d > 0 ? d : 1;
    log_deg[i] = logf((float)dc + 1.0f);         // log(degc + 1)
    c = (double)logf((float)d + 1.0f);           // avg uses raw deg
  }
  sb[threadIdx.x] = c;
  __syncthreads();
  for (int off = 128; off > 0; off >>= 1) {
    if (threadIdx.x < off) sb[threadIdx.x] += sb[threadIdx.x + off];
    __syncthreads();
  }
  if (threadIdx.x == 0) atomicAdd(avgacc, sb[0]);
}

// fused: avg finalize + graph bounds (binary search on sorted batch)
__global__ void avg_gb_kernel(const double* __restrict__ avgacc,
                              float* __restrict__ avgf,
                              const int* __restrict__ batch,
                              int* __restrict__ gcnt)
{
  __shared__ int sb[65];
  int g = threadIdx.x;  // 64 threads
  int lo = 0, hi = N_NODES;
  while (lo < hi) { int mid = (lo + hi) >> 1; if (batch[mid] < g) lo = mid + 1; else hi = mid; }
  sb[g] = lo;
  if (g == 0) { sb[64] = N_NODES; *avgf = (float)(*avgacc / (double)N_NODES); }
  __syncthreads();
  gcnt[g] = sb[g + 1] - sb[g];
}

// ===================== weight prep: fold + bf16 hi/lo, MFMA-swizzled ========
// B layout: [l][cg=c/16][kc=k/8][c15=c%16][ko=k%8] -> B-fragment loads in the
// GEMM are lane-contiguous 1KB wave reads (L2-hot; single cheap producer).

__global__ __launch_bounds__(256) void wprep_kernel(
    const float* __restrict__ conv_w, unsigned short* __restrict__ wh,
    unsigned short* __restrict__ wl)
{
  int idx = blockIdx.x * 256 + threadIdx.x;   // 3*192*576 = 331776 = 1296*256
  int k = idx % 576;
  int c = (idx / 576) % 192;
  int l = idx / (576 * 192);
  int s = c >> 6, j = c & 63;
  const float* CW = conv_w + (size_t)l * 2304 * 64;
  float v;
  if (k < 64) {
    int base = s * 768 + k;
    v = CW[base * 64 + j] + CW[(base + 192) * 64 + j] + CW[(base + 384) * 64 + j];
  } else {
    const int srcseg[8] = {1, 2, 4, 5, 7, 8, 10, 11};
    int q = (k >> 6) - 1;
    int t = k & 63;
    v = CW[(s * 768 + srcseg[q] * 64 + t) * 64 + j];
  }
  unsigned short hh = f2bf_rne(v);
  size_t o = (((size_t)l * 12 + (c >> 4)) * 72 + (k >> 3)) * 128 + (c & 15) * 8 + (k & 7);
  wh[o] = hh;
  wl[o] = f2bf_rne(v - bf2f(hh));
}

__global__ void bprep_kernel(const float* __restrict__ conv_w, float* __restrict__ beff)
{
  int l = blockIdx.x;                 // 3 blocks x 192 threads
  int s = threadIdx.x >> 6, j = threadIdx.x & 63;
  const float* CW = conv_w + (size_t)l * 2304 * 64 + (size_t)(s * 768 + 576) * 64;
  float sum = 0.f;
#pragma unroll
  for (int t = 0; t < 64; t++) sum += CW[t * 64 + j];
  beff[(l * 3 + s) * 64 + j] = sum * 0.0031622776601683794f;   // sqrt(1e-5)
}

// ===================== e-segment aggregation (layer-invariant, once) ========
// A stays CONTIGUOUS [n][KEFF] (coalesced 128B stores); the GEMM's LDS stage
// does the fragment transpose once per 64-row tile (R8 lesson: swizzled
// producer stores cost +40% WRITE_SIZE across 4 kernels).

__global__ __launch_bounds__(256) void agg_e_kernel(
    const float* __restrict__ eattr, const float* __restrict__ edge_w,
    const float* __restrict__ edge_b, const int* __restrict__ row_ptr,
    const int* __restrict__ eids,
    unsigned short* __restrict__ agg_h, unsigned short* __restrict__ agg_l)
{
  int lane = threadIdx.x & 63;
  int quad = lane >> 4, a16 = lane & 15;
  int n = blockIdx.x * 4 + (threadIdx.x >> 6);
  if (n >= N_NODES) return;
  float ew[16];
#pragma unroll
  for (int t = 0; t < 16; t++) ew[t] = edge_w[t * 64 + lane];
  float eb = edge_b[lane];
  int s0 = row_ptr[n], s1 = row_ptr[n + 1];
  float se = 0.f, qe = 0.f, mxe = -3.4e38f, mne = 3.4e38f;

  for (int j = s0; j < s1; j += 4) {
    int idx = j + quad;
    float av = 0.f;
    if (idx < s1) av = eattr[(size_t)eids[idx] * 16 + a16];
    unsigned au = __float_as_uint(av);
    float ea[4];
#pragma unroll
    for (int q = 0; q < 4; q++) {
      float c0 = eb, c1 = 0.f;
#pragma unroll
      for (int t = 0; t < 8; t++) {
        c0 = fmaf(__uint_as_float(__builtin_amdgcn_readlane(au, q * 16 + t)), ew[t], c0);
        c1 = fmaf(__uint_as_float(__builtin_amdgcn_readlane(au, q * 16 + 8 + t)), ew[8 + t], c1);
      }
      ea[q] = c0 + c1;
    }
    int rem = s1 - j;   // wave-uniform
#pragma unroll
    for (int q = 0; q < 4; q++) {
      if (q < rem) {
        se += ea[q]; qe = fmaf(ea[q], ea[q], qe);
        mxe = fmaxf(mxe, ea[q]); mne = fminf(mne, ea[q]);
      }
    }
  }

  int deg = s1 - s0;
  float inv = 1.0f / fmaxf((float)deg, 1.0f);
  bool has = deg > 0;
  float m_e = se * inv, ms_e = qe * inv;
  float sd_e = sqrtf(fmaxf(ms_e - m_e * m_e, 0.f) + 1e-5f);
  float mx_e = has ? mxe : 0.f, mn_e = has ? mne : 0.f;

  unsigned short* bh = agg_h + (size_t)n * KEFF;
  unsigned short* bl = agg_l + (size_t)n * KEFF;
#define W2(off, val) { float _v = (val); unsigned short _h = f2bf_rne(_v); \
                       bh[(off) + lane] = _h; bl[(off) + lane] = f2bf_rne(_v - bf2f(_h)); }
  W2(128, m_e); W2(256, mn_e); W2(384, mx_e); W2(512, sd_e);
#undef W2
}

// ===================== per-layer x-segment aggregation =====================

__global__ __launch_bounds__(256) void agg_x_kernel(
    const float* __restrict__ x, const int* __restrict__ srcs,
    const int* __restrict__ row_ptr,
    unsigned short* __restrict__ agg_h, unsigned short* __restrict__ agg_l)
{
  int lane = threadIdx.x & 63;
  int n = blockIdx.x * 4 + (threadIdx.x >> 6);
  if (n >= N_NODES) return;
  float xd = x[(size_t)n * 64 + lane];
  int s0 = row_ptr[n], s1 = row_ptr[n + 1];
  float sA = 0.f, sB = 0.f, sC = 0.f, sD = 0.f;
  float qA = 0.f, qB = 0.f, qC = 0.f, qD = 0.f;
  float mx0 = -3.4e38f, mx1 = -3.4e38f, mn0 = 3.4e38f, mn1 = 3.4e38f;
  int j = s0;
  for (; j + 7 < s1; j += 8) {
    int e0 = srcs[j],     e1 = srcs[j + 1], e2 = srcs[j + 2], e3 = srcs[j + 3];
    int e4 = srcs[j + 4], e5 = srcs[j + 5], e6 = srcs[j + 6], e7 = srcs[j + 7];
    float x0 = x[(size_t)e0 * 64 + lane];
    float x1 = x[(size_t)e1 * 64 + lane];
    float x2 = x[(size_t)e2 * 64 + lane];
    float x3 = x[(size_t)e3 * 64 + lane];
    float x4 = x[(size_t)e4 * 64 + lane];
    float x5 = x[(size_t)e5 * 64 + lane];
    float x6 = x[(size_t)e6 * 64 + lane];
    float x7 = x[(size_t)e7 * 64 + lane];
    sA += x0; sB += x1; sC += x2; sD += x3;
    sA += x4; sB += x5; sC += x6; sD += x7;
    qA = fmaf(x0, x0, qA); qB = fmaf(x1, x1, qB);
    qC = fmaf(x2, x2, qC); qD = fmaf(x3, x3, qD);
    qA = fmaf(x4, x4, qA); qB = fmaf(x5, x5, qB);
    qC = fmaf(x6, x6, qC); qD = fmaf(x7, x7, qD);
    mx0 = fmaxf(mx0, fmaxf(fmaxf(x0, x1), fmaxf(x2, x3)));
    mx1 = fmaxf(mx1, fmaxf(fmaxf(x4, x5), fmaxf(x6, x7)));
    mn0 = fminf(mn0, fminf(fminf(x0, x1), fminf(x2, x3)));
    mn1 = fminf(mn1, fminf(fminf(x4, x5), fminf(x6, x7)));
  }
  for (; j + 3 < s1; j += 4) {
    int e0 = srcs[j], e1 = srcs[j + 1], e2 = srcs[j + 2], e3 = srcs[j + 3];
    float x0 = x[(size_t)e0 * 64 + lane];
    float x1 = x[(size_t)e1 * 64 + lane];
    float x2 = x[(size_t)e2 * 64 + lane];
    float x3 = x[(size_t)e3 * 64 + lane];
    sA += x0; sB += x1; sC += x2; sD += x3;
    qA = fmaf(x0, x0, qA); qB = fmaf(x1, x1, qB);
    qC = fmaf(x2, x2, qC); qD = fmaf(x3, x3, qD);
    mx0 = fmaxf(mx0, fmaxf(x0, x1)); mx1 = fmaxf(mx1, fmaxf(x2, x3));
    mn0 = fminf(mn0, fminf(x0, x1)); mn1 = fminf(mn1, fminf(x2, x3));
  }
  for (; j < s1; j++) {
    float xa = x[(size_t)srcs[j] * 64 + lane];
    sA += xa; qA = fmaf(xa, xa, qA);
    mx0 = fmaxf(mx0, xa); mn0 = fminf(mn0, xa);
  }
  float sx = (sA + sB) + (sC + sD);
  float qx = (qA + qB) + (qC + qD);
  float mxx = fmaxf(mx0, mx1), mnx = fminf(mn0, mn1);

  int deg = s1 - s0;
  float inv = 1.0f / fmaxf((float)deg, 1.0f);
  bool has = deg > 0;
  float m_s = sx * inv, ms_s = qx * inv;
  float sd_s = sqrtf(fmaxf(ms_s - m_s * m_s, 0.f) + 1e-5f);
  float mx_s = has ? mxx : 0.f, mn_s = has ? mnx : 0.f;

  unsigned short* bh = agg_h + (size_t)n * KEFF;
  unsigned short* bl = agg_l + (size_t)n * KEFF;
#define W2(off, val) { float _v = (val); unsigned short _h = f2bf_rne(_v); \
                       bh[(off) + lane] = _h; bl[(off) + lane] = f2bf_rne(_v - bf2f(_h)); }
  W2(0,   has ? xd : 0.f);
  W2(64,  m_s); W2(192, mn_s); W2(320, mx_s); W2(448, sd_s);
#undef W2
}

// ===================== MFMA GEMM v5: LDS-staged A, direct swizzled B ========
// A contiguous -> LDS transpose (10KB, 2 barriers/iter); B fragments loaded
// straight from the swizzled global layout (coalesced, L2-hot). 256 thr /
// 4 waves, M=64, N=192; wave w owns cols {s*64 + w*16 + l15}.

__global__ __launch_bounds__(256, 3) void gemm_kernel(
    const unsigned short* __restrict__ Ah, const unsigned short* __restrict__ Al,
    const unsigned short* __restrict__ Wh, const unsigned short* __restrict__ Wl,
    const float* __restrict__ beff, const float* __restrict__ bias,
    const float* __restrict__ log_deg, const float* __restrict__ avg_ptr,
    float* __restrict__ h, double* __restrict__ bnacc)
{
  __shared__ __align__(16) short AsH[64 * 40], AsL[64 * 40];
  int tid = threadIdx.x;
  int lane = tid & 63, w = tid >> 6;
  int quad = lane >> 4, l15 = lane & 15;
  int n0 = blockIdx.x * 64;

  int arow = tid >> 2, ac = tid & 3;
  int an = n0 + arow; if (an >= N_NODES) an = N_NODES - 1;
  const unsigned short* gah = Ah + (size_t)an * KEFF + ac * 8;
  const unsigned short* gal = Al + (size_t)an * KEFF + ac * 8;

  // B colgroup base pointers: cg = s*4 + w
  const unsigned short* pbh[3];
  const unsigned short* pbl[3];
#pragma unroll
  for (int s = 0; s < 3; s++) {
    size_t cb = (size_t)(s * 4 + w) * 72 * 128 + l15 * 8;
    pbh[s] = Wh + cb;
    pbl[s] = Wl + cb;
  }

  f32x4 acc[4][3] = {};

  for (int k0 = 0; k0 < KEFF; k0 += 32) {
    *(float4*)(AsH + arow * 40 + ac * 8) = *(const float4*)(gah + k0);
    *(float4*)(AsL + arow * 40 + ac * 8) = *(const float4*)(gal + k0);
    __syncthreads();

    int koff = ((k0 >> 3) + quad) * 128;
    bf16x8 bhf[3], blf[3];
#pragma unroll
    for (int s = 0; s < 3; s++) {
      bhf[s] = *(const bf16x8*)(pbh[s] + koff);
      blf[s] = *(const bf16x8*)(pbl[s] + koff);
    }
#pragma unroll
    for (int i = 0; i < 4; i++) {
      int row = i * 16 + l15;
      bf16x8 ah = *(const bf16x8*)(AsH + row * 40 + quad * 8);
      bf16x8 al = *(const bf16x8*)(AsL + row * 40 + quad * 8);
#pragma unroll
      for (int s = 0; s < 3; s++) {
        acc[i][s] = __builtin_amdgcn_mfma_f32_16x16x32_bf16(ah, bhf[s], acc[i][s], 0, 0, 0);
        acc[i][s] = __builtin_amdgcn_mfma_f32_16x16x32_bf16(al, bhf[s], acc[i][s], 0, 0, 0);
        acc[i][s] = __builtin_amdgcn_mfma_f32_16x16x32_bf16(ah, blf[s], acc[i][s], 0, 0, 0);
      }
    }
    __syncthreads();
  }

  float avg = *avg_ptr;
  int col = w * 16 + l15;
  float be0 = beff[col], be1 = beff[64 + col], be2 = beff[128 + col];
  float bi = bias[col];
  float ss = 0.f, sq = 0.f;
#pragma unroll
  for (int i = 0; i < 4; i++) {
#pragma unroll
    for (int r = 0; r < 4; r++) {
      int n = n0 + i * 16 + quad * 4 + r;
      if (n < N_NODES) {
        float ld = log_deg[n];
        float amp = ld / avg, att = avg / ld;
        float v = (acc[i][0][r] + be0) + amp * (acc[i][1][r] + be1)
                + att * (acc[i][2][r] + be2) + bi;
        h[(size_t)n * 64 + col] = v;
        ss += v; sq = fmaf(v, v, sq);
      }
    }
  }
  // reduce over quads (same col every 16 lanes)
  ss += __shfl_xor(ss, 16, 64); ss += __shfl_xor(ss, 32, 64);
  sq += __shfl_xor(sq, 16, 64); sq += __shfl_xor(sq, 32, 64);
  if (quad == 0) {
    atomicAdd(&bnacc[col], (double)ss);
    atomicAdd(&bnacc[64 + col], (double)sq);
  }
}

// ===================== fused BN finalize + apply =====================
// Each block recomputes mu/scale from bnacc (128 doubles, L2-hot) — cheaper
// than a separate dispatch.

__global__ __launch_bounds__(256) void apply_kernel(
    const float* __restrict__ h, const double* __restrict__ acc,
    const float* __restrict__ g, const float* __restrict__ bnb,
    float* __restrict__ x)
{
  __shared__ float smu[64], ssc[64];
  int tid = threadIdx.x;
  if (tid < 64) {
    double mu = acc[tid] / (double)N_NODES;
    double var = acc[64 + tid] / (double)N_NODES - mu * mu;
    double rstd = 1.0 / sqrt(var + 1e-5);
    smu[tid] = (float)mu;
    ssc[tid] = (float)(rstd * (double)g[tid]);
  }
  __syncthreads();
  int i4 = blockIdx.x * 256 + tid;   // float4 index, exact grid
  const float4* h4 = (const float4*)h;
  float4* x4 = (float4*)x;
  int c4 = (i4 & 15) * 4;
  float4 hv = h4[i4], xv = x4[i4];
  float4 bb = ((const float4*)bnb)[i4 & 15];
  float4 r;
  r.x = fmaxf((hv.x - smu[c4])     * ssc[c4]     + bb.x, 0.f) + xv.x;
  r.y = fmaxf((hv.y - smu[c4 + 1]) * ssc[c4 + 1] + bb.y, 0.f) + xv.y;
  r.z = fmaxf((hv.z - smu[c4 + 2]) * ssc[c4 + 2] + bb.z, 0.f) + xv.z;
  r.w = fmaxf((hv.w - smu[c4 + 3]) * ssc[c4 + 3] + bb.w, 0.f) + xv.w;
  x4[i4] = r;
}

// ===================== pooling + head =====================

__global__ __launch_bounds__(256) void pool_kernel(
    const float* __restrict__ x, const int* __restrict__ batch,
    float* __restrict__ gsum)
{
  int tid = threadIdx.x;
  int j = tid & 63, ri = tid >> 6;
  float acc = 0.f; int cur = -1;
  for (int k = 0; k < 16; k++) {
    int n = blockIdx.x * 64 + k * 4 + ri;
    if (n < N_NODES) {
      int b = batch[n];
      if (b != cur) {
        if (cur >= 0) atomicAdd(&gsum[cur * 64 + j], acc);
        cur = b; acc = 0.f;
      }
      acc += x[(size_t)n * 64 + j];
    }
  }
  if (cur >= 0) atomicAdd(&gsum[cur * 64 + j], acc);
}

__global__ void fc_kernel(const float* __restrict__ gsum, const int* __restrict__ gcnt,
                          const float* __restrict__ w1, const float* __restrict__ b1,
                          const float* __restrict__ w2, const float* __restrict__ b2,
                          const float* __restrict__ w3, const float* __restrict__ b3,
                          float* __restrict__ out)
{
  int g = threadIdx.x;  // 64 threads, one per graph
  float cnt = fmaxf((float)gcnt[g], 1.0f);
  float gv[64];
#pragma unroll
  for (int j = 0; j < 64; j++) gv[j] = gsum[g * 64 + j] / cnt;
  float a1[32];
#pragma unroll
  for (int o = 0; o < 32; o++) {
    float s = b1[o];
#pragma unroll
    for (int j = 0; j < 64; j++) s = fmaf(gv[j], w1[j * 32 + o], s);
    a1[o] = fmaxf(s, 0.f);
  }
  float a2[16];
#pragma unroll
  for (int o = 0; o < 16; o++) {
    float s = b2[o];
#pragma unroll
    for (int j = 0; j < 32; j++) s = fmaf(a1[j], w2[j * 16 + o], s);
    a2[o] = fmaxf(s, 0.f);
  }
#pragma unroll
  for (int o = 0; o < 10; o++) {
    float s = b3[o];
#pragma unroll
    for (int j = 0; j < 16; j++) s = fmaf(a2[j], w3[j * 10 + o], s);
    out[g * 10 + o] = s;
  }
}

// ===================== launch =====================

extern "C" void kernel_launch(void* const* d_in, const int* in_sizes, int n_in,
                              void* d_out, int out_size, void* d_ws, size_t ws_size,
                              hipStream_t stream)
{
  (void)in_sizes; (void)n_in; (void)out_size; (void)ws_size;
  const float* xin    = (const float*)d_in[0];
  const int*   ei     = (const int*)d_in[1];
  const int*   batch  = (const int*)d_in[2];
  const float* eattr  = (const float*)d_in[3];
  const float* node_w = (const float*)d_in[4];
  const float* node_b = (const float*)d_in[5];
  const float* edge_w = (const float*)d_in[6];
  const float* edge_b = (const float*)d_in[7];
  const float* conv_w = (const float*)d_in[8];
  const float* conv_b = (const float*)d_in[9];
  const float* bn_g   = (const float*)d_in[10];
  const float* bn_b   = (const float*)d_in[11];
  const float* fc1_w  = (const float*)d_in[12];
  const float* fc1_b  = (const float*)d_in[13];
  const float* fc2_w  = (const float*)d_in[14];
  const float* fc2_b  = (const float*)d_in[15];
  const float* fc3_w  = (const float*)d_in[16];
  const float* fc3_b  = (const float*)d_in[17];
  float* out = (float*)d_out;
  const int* srcp = ei;
  const int* dstp = ei + N_EDGES;

  char* p = (char*)d_ws;
  auto alloc = [&](size_t b) { char* r = p; p += (b + 255) & ~(size_t)255; return (void*)r; };
  float*  x       = (float*)alloc((size_t)N_NODES * 64 * 4);
  float*  h       = (float*)alloc((size_t)N_NODES * 64 * 4);
  unsigned short* agg_h = (unsigned short*)alloc((size_t)N_NODES * KEFF * 2);
  unsigned short* agg_l = (unsigned short*)alloc((size_t)N_NODES * KEFF * 2);
  unsigned short* wh    = (unsigned short*)alloc((size_t)3 * 12 * 72 * 128 * 2);
  unsigned short* wl    = (unsigned short*)alloc((size_t)3 * 12 * 72 * 128 * 2);
  int*    srcs    = (int*)alloc((size_t)N_EDGES * 4);
  int*    eids    = (int*)alloc((size_t)N_EDGES * 4);
  float*  beff    = (float*)alloc((size_t)3 * 3 * 64 * 4);
  int*    row_ptr = (int*)alloc((N_NODES + 1) * 4);
  int*    cursor  = (int*)alloc((size_t)N_NODES * 4);
  int*    cnt     = (int*)alloc((size_t)N_NODES * 4);
  float*  log_deg = (float*)alloc((size_t)N_NODES * 4);
  int*    bsum    = (int*)alloc(256 * 4);
  int*    boff    = (int*)alloc(256 * 4);
  double* avgacc  = (double*)alloc(256);
  float*  avgf    = (float*)alloc(256);
  double* bnacc   = (double*)alloc(3 * 128 * 8);
  float*  muf     = (float*)alloc(256);
  float*  scf     = (float*)alloc(256);
  float*  gsum    = (float*)alloc((size_t)NGRAPH * 64 * 4);
  int*    gcnt    = (int*)alloc((size_t)NGRAPH * 4);
  (void)muf; (void)scf;

  zero_kernel<<<213, 256, 0, stream>>>(cnt, gsum, bnacc, avgacc);
  node_enc_kernel<<<12500, 256, 0, stream>>>(xin, node_w, node_b, x);
  count_kernel<<<3125, 256, 0, stream>>>(dstp, cnt);
  scan_a_kernel<<<196, 256, 0, stream>>>(cnt, bsum);
  scan_b_kernel<<<1, 256, 0, stream>>>(bsum, boff);
  scan_c_kernel<<<196, 256, 0, stream>>>(cnt, boff, row_ptr, cursor);
  fill_kernel<<<3125, 256, 0, stream>>>(srcp, dstp, cursor, srcs, eids);
  deg_log_kernel<<<196, 256, 0, stream>>>(cnt, log_deg, avgacc);
  avg_gb_kernel<<<1, 64, 0, stream>>>(avgacc, avgf, batch, gcnt);
  wprep_kernel<<<1296, 256, 0, stream>>>(conv_w, wh, wl);
  bprep_kernel<<<3, 192, 0, stream>>>(conv_w, beff);

  agg_e_kernel<<<12500, 256, 0, stream>>>(eattr, edge_w, edge_b, row_ptr,
                                          eids, agg_h, agg_l);

  for (int l = 0; l < 3; l++) {
    agg_x_kernel<<<12500, 256, 0, stream>>>(x, srcs, row_ptr, agg_h, agg_l);
    gemm_kernel<<<782, 256, 0, stream>>>(agg_h, agg_l,
                                         wh + (size_t)l * 12 * 72 * 128,
                                         wl + (size_t)l * 12 * 72 * 128,
                                         beff + l * 192, conv_b + l * 64,
                                         log_deg, avgf, h, bnacc + l * 128);
    apply_kernel<<<3125, 256, 0, stream>>>(h, bnacc + l * 128, bn_g + l * 64,
                                           bn_b + l * 64, x);
  }

  pool_kernel<<<782, 256, 0, stream>>>(x, batch, gsum);
  fc_kernel<<<1, 64, 0, stream>>>(gsum, gcnt, fc1_w, fc1_b, fc2_w, fc2_b,
                                  fc3_w, fc3_b, out);
}

// Round 10
// 663.747 us; speedup vs baseline: 1.3724x; 1.0285x over previous
//
#include <hip/hip_runtime.h>
#include <math.h>

#define N_NODES 50000
#define N_EDGES 800000
#define NGRAPH  64
#define KEFF    576   // compressed agg width (768->576 via x_dst folding)

typedef short bf16x8 __attribute__((ext_vector_type(8)));
typedef float f32x4  __attribute__((ext_vector_type(4)));

__device__ inline unsigned short f2bf_rne(float f) {
  unsigned u = __float_as_uint(f);
  unsigned r = u + 0x7FFFu + ((u >> 16) & 1u);
  return (unsigned short)(r >> 16);
}
__device__ inline float bf2f(unsigned short h) {
  return __uint_as_float(((unsigned)h) << 16);
}

// ===================== setup kernels =====================

// one kernel zeroes everything (replaces 4 memset dispatches)
__global__ __launch_bounds__(256) void zero_kernel(
    int* __restrict__ cnt, float* __restrict__ gsum,
    double* __restrict__ bnacc, double* __restrict__ avgacc)
{
  int i = blockIdx.x * 256 + threadIdx.x;   // grid 213 -> 54528
  if (i < N_NODES) { cnt[i] = 0; return; }
  int j = i - N_NODES;
  if (j < NGRAPH * 64) { gsum[j] = 0.f; return; }
  int k = j - NGRAPH * 64;
  if (k < 3 * 128) { bnacc[k] = 0.0; return; }
  if (k == 3 * 128) *avgacc = 0.0;
}

__global__ __launch_bounds__(256) void node_enc_kernel(
    const float* __restrict__ xin, const float* __restrict__ nw,
    const float* __restrict__ nb, float* __restrict__ x)
{
  __shared__ float xs[256];
  int tid = threadIdx.x;
  int base = blockIdx.x * 256;          // 4 nodes per block
  xs[tid] = xin[base + tid];
  __syncthreads();
  int r = tid >> 6, j = tid & 63;
  float acc = nb[j];
#pragma unroll
  for (int t = 0; t < 64; t++) acc = fmaf(xs[r * 64 + t], nw[t * 64 + j], acc);
  x[base + tid] = acc;
}

__global__ void count_kernel(const int* __restrict__ dst, int* __restrict__ cnt)
{
  int e = blockIdx.x * 256 + threadIdx.x;   // grid exactly covers E
  atomicAdd(&cnt[dst[e]], 1);
}

__global__ __launch_bounds__(256) void scan_a_kernel(
    const int* __restrict__ cnt, int* __restrict__ bsum)
{
  __shared__ int s[256];
  int i = blockIdx.x * 256 + threadIdx.x;
  s[threadIdx.x] = (i < N_NODES) ? cnt[i] : 0;
  __syncthreads();
  for (int off = 128; off > 0; off >>= 1) {
    if (threadIdx.x < off) s[threadIdx.x] += s[threadIdx.x + off];
    __syncthreads();
  }
  if (threadIdx.x == 0) bsum[blockIdx.x] = s[0];
}

__global__ __launch_bounds__(256) void scan_b_kernel(
    const int* __restrict__ bsum, int* __restrict__ boff)
{
  __shared__ int s[256];
  int tid = threadIdx.x;
  int v = (tid < 196) ? bsum[tid] : 0;
  s[tid] = v;
  __syncthreads();
  for (int off = 1; off < 256; off <<= 1) {
    int t = (tid >= off) ? s[tid - off] : 0;
    __syncthreads();
    s[tid] += t;
    __syncthreads();
  }
  boff[tid] = s[tid] - v;   // exclusive prefix of block sums
}

__global__ __launch_bounds__(256) void scan_c_kernel(
    const int* __restrict__ cnt, const int* __restrict__ boff,
    int* __restrict__ row_ptr, int* __restrict__ cursor)
{
  __shared__ int s[256];
  int tid = threadIdx.x;
  int i = blockIdx.x * 256 + tid;
  int v = (i < N_NODES) ? cnt[i] : 0;
  s[tid] = v;
  __syncthreads();
  for (int off = 1; off < 256; off <<= 1) {
    int t = (tid >= off) ? s[tid - off] : 0;
    __syncthreads();
    s[tid] += t;
    __syncthreads();
  }
  int incl = s[tid];
  int base = boff[blockIdx.x];
  if (i < N_NODES) { row_ptr[i] = base + incl - v; cursor[i] = base + incl - v; }
  if (i == N_NODES - 1) row_ptr[N_NODES] = base + incl;
}

__global__ void fill_kernel(const int* __restrict__ src, const int* __restrict__ dst,
                            int* __restrict__ cursor, int* __restrict__ srcs,
                            int* __restrict__ eids)
{
  int e = blockIdx.x * 256 + threadIdx.x;
  int d = dst[e];
  int pos = atomicAdd(&cursor[d], 1);
  srcs[pos] = src[e];
  eids[pos] = e;
}

__global__ __launch_bounds__(256) void deg_log_kernel(
    const int* __restrict__ cnt, float* __restrict__ log_deg,
    double* __restrict__ avgacc)
{
  __shared__ double sb[256];
  int i = blockIdx.x * 256 + threadIdx.x;
  double c = 0.0;
  if (i < N_NODES) {
    int d = cnt[i];
    int dc = d > 0 ? d : 1;
    log_deg[i] = logf((float)dc + 1.0f);         // log(degc + 1)
    c = (double)logf((float)d + 1.0f);           // avg uses raw deg
  }
  sb[threadIdx.x] = c;
  __syncthreads();
  for (int off = 128; off > 0; off >>= 1) {
    if (threadIdx.x < off) sb[threadIdx.x] += sb[threadIdx.x + off];
    __syncthreads();
  }
  if (threadIdx.x == 0) atomicAdd(avgacc, sb[0]);
}

// fused: avg finalize + graph bounds (binary search on sorted batch)
__global__ void avg_gb_kernel(const double* __restrict__ avgacc,
                              float* __restrict__ avgf,
                              const int* __restrict__ batch,
                              int* __restrict__ gcnt)
{
  __shared__ int sb[65];
  int g = threadIdx.x;  // 64 threads
  int lo = 0, hi = N_NODES;
  while (lo < hi) { int mid = (lo + hi) >> 1; if (batch[mid] < g) lo = mid + 1; else hi = mid; }
  sb[g] = lo;
  if (g == 0) { sb[64] = N_NODES; *avgf = (float)(*avgacc / (double)N_NODES); }
  __syncthreads();
  gcnt[g] = sb[g + 1] - sb[g];
}

// ===================== weight prep: fold + bf16 hi/lo, MFMA-swizzled ========
// B layout: [l][cg=c/16][kc=k/8][c15=c%16][ko=k%8] -> B-fragment loads in the
// GEMM are lane-contiguous 1KB wave reads (L2-hot; single cheap producer).

__global__ __launch_bounds__(256) void wprep_kernel(
    const float* __restrict__ conv_w, unsigned short* __restrict__ wh,
    unsigned short* __restrict__ wl)
{
  int idx = blockIdx.x * 256 + threadIdx.x;   // 3*192*576 = 331776 = 1296*256
  int k = idx % 576;
  int c = (idx / 576) % 192;
  int l = idx / (576 * 192);
  int s = c >> 6, j = c & 63;
  const float* CW = conv_w + (size_t)l * 2304 * 64;
  float v;
  if (k < 64) {
    int base = s * 768 + k;
    v = CW[base * 64 + j] + CW[(base + 192) * 64 + j] + CW[(base + 384) * 64 + j];
  } else {
    const int srcseg[8] = {1, 2, 4, 5, 7, 8, 10, 11};
    int q = (k >> 6) - 1;
    int t = k & 63;
    v = CW[(s * 768 + srcseg[q] * 64 + t) * 64 + j];
  }
  unsigned short hh = f2bf_rne(v);
  size_t o = (((size_t)l * 12 + (c >> 4)) * 72 + (k >> 3)) * 128 + (c & 15) * 8 + (k & 7);
  wh[o] = hh;
  wl[o] = f2bf_rne(v - bf2f(hh));
}

__global__ void bprep_kernel(const float* __restrict__ conv_w, float* __restrict__ beff)
{
  int l = blockIdx.x;                 // 3 blocks x 192 threads
  int s = threadIdx.x >> 6, j = threadIdx.x & 63;
  const float* CW = conv_w + (size_t)l * 2304 * 64 + (size_t)(s * 768 + 576) * 64;
  float sum = 0.f;
#pragma unroll
  for (int t = 0; t < 64; t++) sum += CW[t * 64 + j];
  beff[(l * 3 + s) * 64 + j] = sum * 0.0031622776601683794f;   // sqrt(1e-5)
}

// ===================== e-segment aggregation (layer-invariant, once) ========

__global__ __launch_bounds__(256) void agg_e_kernel(
    const float* __restrict__ eattr, const float* __restrict__ edge_w,
    const float* __restrict__ edge_b, const int* __restrict__ row_ptr,
    const int* __restrict__ eids,
    unsigned short* __restrict__ agg_h, unsigned short* __restrict__ agg_l)
{
  int lane = threadIdx.x & 63;
  int quad = lane >> 4, a16 = lane & 15;
  int n = blockIdx.x * 4 + (threadIdx.x >> 6);
  if (n >= N_NODES) return;
  float ew[16];
#pragma unroll
  for (int t = 0; t < 16; t++) ew[t] = edge_w[t * 64 + lane];
  float eb = edge_b[lane];
  int s0 = row_ptr[n], s1 = row_ptr[n + 1];
  float se = 0.f, qe = 0.f, mxe = -3.4e38f, mne = 3.4e38f;

  for (int j = s0; j < s1; j += 4) {
    int idx = j + quad;
    float av = 0.f;
    if (idx < s1) av = eattr[(size_t)eids[idx] * 16 + a16];
    unsigned au = __float_as_uint(av);
    float ea[4];
#pragma unroll
    for (int q = 0; q < 4; q++) {
      float c0 = eb, c1 = 0.f;
#pragma unroll
      for (int t = 0; t < 8; t++) {
        c0 = fmaf(__uint_as_float(__builtin_amdgcn_readlane(au, q * 16 + t)), ew[t], c0);
        c1 = fmaf(__uint_as_float(__builtin_amdgcn_readlane(au, q * 16 + 8 + t)), ew[8 + t], c1);
      }
      ea[q] = c0 + c1;
    }
    int rem = s1 - j;   // wave-uniform
#pragma unroll
    for (int q = 0; q < 4; q++) {
      if (q < rem) {
        se += ea[q]; qe = fmaf(ea[q], ea[q], qe);
        mxe = fmaxf(mxe, ea[q]); mne = fminf(mne, ea[q]);
      }
    }
  }

  int deg = s1 - s0;
  float inv = 1.0f / fmaxf((float)deg, 1.0f);
  bool has = deg > 0;
  float m_e = se * inv, ms_e = qe * inv;
  float sd_e = sqrtf(fmaxf(ms_e - m_e * m_e, 0.f) + 1e-5f);
  float mx_e = has ? mxe : 0.f, mn_e = has ? mne : 0.f;

  unsigned short* bh = agg_h + (size_t)n * KEFF;
  unsigned short* bl = agg_l + (size_t)n * KEFF;
#define W2(off, val) { float _v = (val); unsigned short _h = f2bf_rne(_v); \
                       bh[(off) + lane] = _h; bl[(off) + lane] = f2bf_rne(_v - bf2f(_h)); }
  W2(128, m_e); W2(256, mn_e); W2(384, mx_e); W2(512, sd_e);
#undef W2
}

// ===================== per-layer x-segment aggregation =====================
// x8 unroll with MASKED single-iteration tail: remainder edges (deg%8) are
// gathered in parallel with clamped indices (min/max take the valid
// duplicate; sum/sumsq masked to 0) instead of up to 7 serial gathers.

__global__ __launch_bounds__(256) void agg_x_kernel(
    const float* __restrict__ x, const int* __restrict__ srcs,
    const int* __restrict__ row_ptr,
    unsigned short* __restrict__ agg_h, unsigned short* __restrict__ agg_l)
{
  int lane = threadIdx.x & 63;
  int n = blockIdx.x * 4 + (threadIdx.x >> 6);
  if (n >= N_NODES) return;
  float xd = x[(size_t)n * 64 + lane];
  int s0 = row_ptr[n], s1 = row_ptr[n + 1];
  float sA = 0.f, sB = 0.f, sC = 0.f, sD = 0.f;
  float qA = 0.f, qB = 0.f, qC = 0.f, qD = 0.f;
  float mx0 = -3.4e38f, mx1 = -3.4e38f, mn0 = 3.4e38f, mn1 = 3.4e38f;
  int j = s0;
  for (; j + 7 < s1; j += 8) {
    int e0 = srcs[j],     e1 = srcs[j + 1], e2 = srcs[j + 2], e3 = srcs[j + 3];
    int e4 = srcs[j + 4], e5 = srcs[j + 5], e6 = srcs[j + 6], e7 = srcs[j + 7];
    float x0 = x[(size_t)e0 * 64 + lane];
    float x1 = x[(size_t)e1 * 64 + lane];
    float x2 = x[(size_t)e2 * 64 + lane];
    float x3 = x[(size_t)e3 * 64 + lane];
    float x4 = x[(size_t)e4 * 64 + lane];
    float x5 = x[(size_t)e5 * 64 + lane];
    float x6 = x[(size_t)e6 * 64 + lane];
    float x7 = x[(size_t)e7 * 64 + lane];
    sA += x0; sB += x1; sC += x2; sD += x3;
    sA += x4; sB += x5; sC += x6; sD += x7;
    qA = fmaf(x0, x0, qA); qB = fmaf(x1, x1, qB);
    qC = fmaf(x2, x2, qC); qD = fmaf(x3, x3, qD);
    qA = fmaf(x4, x4, qA); qB = fmaf(x5, x5, qB);
    qC = fmaf(x6, x6, qC); qD = fmaf(x7, x7, qD);
    mx0 = fmaxf(mx0, fmaxf(fmaxf(x0, x1), fmaxf(x2, x3)));
    mx1 = fmaxf(mx1, fmaxf(fmaxf(x4, x5), fmaxf(x6, x7)));
    mn0 = fminf(mn0, fminf(fminf(x0, x1), fminf(x2, x3)));
    mn1 = fminf(mn1, fminf(fminf(x4, x5), fminf(x6, x7)));
  }
  if (j < s1) {                       // masked tail: 1..7 edges, 8 gathers in flight
    int last = s1 - 1;
    int rem = s1 - j;                 // wave-uniform
    int e0 = srcs[j];
    int e1 = srcs[j + 1 < s1 ? j + 1 : last];
    int e2 = srcs[j + 2 < s1 ? j + 2 : last];
    int e3 = srcs[j + 3 < s1 ? j + 3 : last];
    int e4 = srcs[j + 4 < s1 ? j + 4 : last];
    int e5 = srcs[j + 5 < s1 ? j + 5 : last];
    int e6 = srcs[j + 6 < s1 ? j + 6 : last];
    int e7 = srcs[j + 7 < s1 ? j + 7 : last];
    float x0 = x[(size_t)e0 * 64 + lane];
    float x1 = x[(size_t)e1 * 64 + lane];
    float x2 = x[(size_t)e2 * 64 + lane];
    float x3 = x[(size_t)e3 * 64 + lane];
    float x4 = x[(size_t)e4 * 64 + lane];
    float x5 = x[(size_t)e5 * 64 + lane];
    float x6 = x[(size_t)e6 * 64 + lane];
    float x7 = x[(size_t)e7 * 64 + lane];
    // min/max: clamped duplicates are valid edge values -> harmless
    mx0 = fmaxf(mx0, fmaxf(fmaxf(x0, x1), fmaxf(x2, x3)));
    mx1 = fmaxf(mx1, fmaxf(fmaxf(x4, x5), fmaxf(x6, x7)));
    mn0 = fminf(mn0, fminf(fminf(x0, x1), fminf(x2, x3)));
    mn1 = fminf(mn1, fminf(fminf(x4, x5), fminf(x6, x7)));
    // sum/sumsq: zero the pad slots
    float z1 = 1 < rem ? x1 : 0.f;
    float z2 = 2 < rem ? x2 : 0.f;
    float z3 = 3 < rem ? x3 : 0.f;
    float z4 = 4 < rem ? x4 : 0.f;
    float z5 = 5 < rem ? x5 : 0.f;
    float z6 = 6 < rem ? x6 : 0.f;
    float z7 = 7 < rem ? x7 : 0.f;
    sA += x0; sB += z1; sC += z2; sD += z3;
    sA += z4; sB += z5; sC += z6; sD += z7;
    qA = fmaf(x0, x0, qA); qB = fmaf(z1, z1, qB);
    qC = fmaf(z2, z2, qC); qD = fmaf(z3, z3, qD);
    qA = fmaf(z4, z4, qA); qB = fmaf(z5, z5, qB);
    qC = fmaf(z6, z6, qC); qD = fmaf(z7, z7, qD);
  }
  float sx = (sA + sB) + (sC + sD);
  float qx = (qA + qB) + (qC + qD);
  float mxx = fmaxf(mx0, mx1), mnx = fminf(mn0, mn1);

  int deg = s1 - s0;
  float inv = 1.0f / fmaxf((float)deg, 1.0f);
  bool has = deg > 0;
  float m_s = sx * inv, ms_s = qx * inv;
  float sd_s = sqrtf(fmaxf(ms_s - m_s * m_s, 0.f) + 1e-5f);
  float mx_s = has ? mxx : 0.f, mn_s = has ? mnx : 0.f;

  unsigned short* bh = agg_h + (size_t)n * KEFF;
  unsigned short* bl = agg_l + (size_t)n * KEFF;
#define W2(off, val) { float _v = (val); unsigned short _h = f2bf_rne(_v); \
                       bh[(off) + lane] = _h; bl[(off) + lane] = f2bf_rne(_v - bf2f(_h)); }
  W2(0,   has ? xd : 0.f);
  W2(64,  m_s); W2(192, mn_s); W2(320, mx_s); W2(448, sd_s);
#undef W2
}

// ===================== MFMA GEMM v6: pipelined LDS-A, direct swizzled B ====
// A chunk k+1 prefetched into registers before the barrier (latency hidden
// behind the MFMA section); B-frag loads issued first so the compiler's
// vmcnt for B uses leaves the A-prefetch in flight.

__global__ __launch_bounds__(256, 3) void gemm_kernel(
    const unsigned short* __restrict__ Ah, const unsigned short* __restrict__ Al,
    const unsigned short* __restrict__ Wh, const unsigned short* __restrict__ Wl,
    const float* __restrict__ beff, const float* __restrict__ bias,
    const float* __restrict__ log_deg, const float* __restrict__ avg_ptr,
    float* __restrict__ h, double* __restrict__ bnacc)
{
  __shared__ __align__(16) short AsH[64 * 40], AsL[64 * 40];
  int tid = threadIdx.x;
  int lane = tid & 63, w = tid >> 6;
  int quad = lane >> 4, l15 = lane & 15;
  int n0 = blockIdx.x * 64;

  int arow = tid >> 2, ac = tid & 3;
  int an = n0 + arow; if (an >= N_NODES) an = N_NODES - 1;
  const unsigned short* gah = Ah + (size_t)an * KEFF + ac * 8;
  const unsigned short* gal = Al + (size_t)an * KEFF + ac * 8;

  // B colgroup base pointers: cg = s*4 + w
  const unsigned short* pbh[3];
  const unsigned short* pbl[3];
#pragma unroll
  for (int s = 0; s < 3; s++) {
    size_t cb = (size_t)(s * 4 + w) * 72 * 128 + l15 * 8;
    pbh[s] = Wh + cb;
    pbl[s] = Wl + cb;
  }

  f32x4 acc[4][3] = {};
  float4 rh = *(const float4*)(gah);
  float4 rl = *(const float4*)(gal);

  for (int k0 = 0; k0 < KEFF; k0 += 32) {
    // B frags for this chunk (independent of LDS state)
    int koff = ((k0 >> 3) + quad) * 128;
    bf16x8 bhf[3], blf[3];
#pragma unroll
    for (int s = 0; s < 3; s++) {
      bhf[s] = *(const bf16x8*)(pbh[s] + koff);
      blf[s] = *(const bf16x8*)(pbl[s] + koff);
    }
    // publish current A chunk
    *(float4*)(AsH + arow * 40 + ac * 8) = rh;
    *(float4*)(AsL + arow * 40 + ac * 8) = rl;
    // prefetch next A chunk (consumed after the next barrier pair)
    if (k0 + 32 < KEFF) {
      rh = *(const float4*)(gah + k0 + 32);
      rl = *(const float4*)(gal + k0 + 32);
    }
    __syncthreads();

#pragma unroll
    for (int i = 0; i < 4; i++) {
      int row = i * 16 + l15;
      bf16x8 ah = *(const bf16x8*)(AsH + row * 40 + quad * 8);
      bf16x8 al = *(const bf16x8*)(AsL + row * 40 + quad * 8);
#pragma unroll
      for (int s = 0; s < 3; s++) {
        acc[i][s] = __builtin_amdgcn_mfma_f32_16x16x32_bf16(ah, bhf[s], acc[i][s], 0, 0, 0);
        acc[i][s] = __builtin_amdgcn_mfma_f32_16x16x32_bf16(al, bhf[s], acc[i][s], 0, 0, 0);
        acc[i][s] = __builtin_amdgcn_mfma_f32_16x16x32_bf16(ah, blf[s], acc[i][s], 0, 0, 0);
      }
    }
    __syncthreads();
  }

  float avg = *avg_ptr;
  int col = w * 16 + l15;
  float be0 = beff[col], be1 = beff[64 + col], be2 = beff[128 + col];
  float bi = bias[col];
  float ss = 0.f, sq = 0.f;
#pragma unroll
  for (int i = 0; i < 4; i++) {
#pragma unroll
    for (int r = 0; r < 4; r++) {
      int n = n0 + i * 16 + quad * 4 + r;
      if (n < N_NODES) {
        float ld = log_deg[n];
        float amp = ld / avg, att = avg / ld;
        float v = (acc[i][0][r] + be0) + amp * (acc[i][1][r] + be1)
                + att * (acc[i][2][r] + be2) + bi;
        h[(size_t)n * 64 + col] = v;
        ss += v; sq = fmaf(v, v, sq);
      }
    }
  }
  // reduce over quads (same col every 16 lanes)
  ss += __shfl_xor(ss, 16, 64); ss += __shfl_xor(ss, 32, 64);
  sq += __shfl_xor(sq, 16, 64); sq += __shfl_xor(sq, 32, 64);
  if (quad == 0) {
    atomicAdd(&bnacc[col], (double)ss);
    atomicAdd(&bnacc[64 + col], (double)sq);
  }
}

// ===================== fused BN finalize + apply =====================

__global__ __launch_bounds__(256) void apply_kernel(
    const float* __restrict__ h, const double* __restrict__ acc,
    const float* __restrict__ g, const float* __restrict__ bnb,
    float* __restrict__ x)
{
  __shared__ float smu[64], ssc[64];
  int tid = threadIdx.x;
  if (tid < 64) {
    double mu = acc[tid] / (double)N_NODES;
    double var = acc[64 + tid] / (double)N_NODES - mu * mu;
    double rstd = 1.0 / sqrt(var + 1e-5);
    smu[tid] = (float)mu;
    ssc[tid] = (float)(rstd * (double)g[tid]);
  }
  __syncthreads();
  int i4 = blockIdx.x * 256 + tid;   // float4 index, exact grid
  const float4* h4 = (const float4*)h;
  float4* x4 = (float4*)x;
  int c4 = (i4 & 15) * 4;
  float4 hv = h4[i4], xv = x4[i4];
  float4 bb = ((const float4*)bnb)[i4 & 15];
  float4 r;
  r.x = fmaxf((hv.x - smu[c4])     * ssc[c4]     + bb.x, 0.f) + xv.x;
  r.y = fmaxf((hv.y - smu[c4 + 1]) * ssc[c4 + 1] + bb.y, 0.f) + xv.y;
  r.z = fmaxf((hv.z - smu[c4 + 2]) * ssc[c4 + 2] + bb.z, 0.f) + xv.z;
  r.w = fmaxf((hv.w - smu[c4 + 3]) * ssc[c4 + 3] + bb.w, 0.f) + xv.w;
  x4[i4] = r;
}

// ===================== pooling + head =====================

__global__ __launch_bounds__(256) void pool_kernel(
    const float* __restrict__ x, const int* __restrict__ batch,
    float* __restrict__ gsum)
{
  int tid = threadIdx.x;
  int j = tid & 63, ri = tid >> 6;
  float acc = 0.f; int cur = -1;
  for (int k = 0; k < 16; k++) {
    int n = blockIdx.x * 64 + k * 4 + ri;
    if (n < N_NODES) {
      int b = batch[n];
      if (b != cur) {
        if (cur >= 0) atomicAdd(&gsum[cur * 64 + j], acc);
        cur = b; acc = 0.f;
      }
      acc += x[(size_t)n * 64 + j];
    }
  }
  if (cur >= 0) atomicAdd(&gsum[cur * 64 + j], acc);
}

__global__ void fc_kernel(const float* __restrict__ gsum, const int* __restrict__ gcnt,
                          const float* __restrict__ w1, const float* __restrict__ b1,
                          const float* __restrict__ w2, const float* __restrict__ b2,
                          const float* __restrict__ w3, const float* __restrict__ b3,
                          float* __restrict__ out)
{
  int g = threadIdx.x;  // 64 threads, one per graph
  float cnt = fmaxf((float)gcnt[g], 1.0f);
  float gv[64];
#pragma unroll
  for (int j = 0; j < 64; j++) gv[j] = gsum[g * 64 + j] / cnt;
  float a1[32];
#pragma unroll
  for (int o = 0; o < 32; o++) {
    float s = b1[o];
#pragma unroll
    for (int j = 0; j < 64; j++) s = fmaf(gv[j], w1[j * 32 + o], s);
    a1[o] = fmaxf(s, 0.f);
  }
  float a2[16];
#pragma unroll
  for (int o = 0; o < 16; o++) {
    float s = b2[o];
#pragma unroll
    for (int j = 0; j < 32; j++) s = fmaf(a1[j], w2[j * 16 + o], s);
    a2[o] = fmaxf(s, 0.f);
  }
#pragma unroll
  for (int o = 0; o < 10; o++) {
    float s = b3[o];
#pragma unroll
    for (int j = 0; j < 16; j++) s = fmaf(a2[j], w3[j * 10 + o], s);
    out[g * 10 + o] = s;
  }
}

// ===================== launch =====================

extern "C" void kernel_launch(void* const* d_in, const int* in_sizes, int n_in,
                              void* d_out, int out_size, void* d_ws, size_t ws_size,
                              hipStream_t stream)
{
  (void)in_sizes; (void)n_in; (void)out_size; (void)ws_size;
  const float* xin    = (const float*)d_in[0];
  const int*   ei     = (const int*)d_in[1];
  const int*   batch  = (const int*)d_in[2];
  const float* eattr  = (const float*)d_in[3];
  const float* node_w = (const float*)d_in[4];
  const float* node_b = (const float*)d_in[5];
  const float* edge_w = (const float*)d_in[6];
  const float* edge_b = (const float*)d_in[7];
  const float* conv_w = (const float*)d_in[8];
  const float* conv_b = (const float*)d_in[9];
  const float* bn_g   = (const float*)d_in[10];
  const float* bn_b   = (const float*)d_in[11];
  const float* fc1_w  = (const float*)d_in[12];
  const float* fc1_b  = (const float*)d_in[13];
  const float* fc2_w  = (const float*)d_in[14];
  const float* fc2_b  = (const float*)d_in[15];
  const float* fc3_w  = (const float*)d_in[16];
  const float* fc3_b  = (const float*)d_in[17];
  float* out = (float*)d_out;
  const int* srcp = ei;
  const int* dstp = ei + N_EDGES;

  char* p = (char*)d_ws;
  auto alloc = [&](size_t b) { char* r = p; p += (b + 255) & ~(size_t)255; return (void*)r; };
  float*  x       = (float*)alloc((size_t)N_NODES * 64 * 4);
  float*  h       = (float*)alloc((size_t)N_NODES * 64 * 4);
  unsigned short* agg_h = (unsigned short*)alloc((size_t)N_NODES * KEFF * 2);
  unsigned short* agg_l = (unsigned short*)alloc((size_t)N_NODES * KEFF * 2);
  unsigned short* wh    = (unsigned short*)alloc((size_t)3 * 12 * 72 * 128 * 2);
  unsigned short* wl    = (unsigned short*)alloc((size_t)3 * 12 * 72 * 128 * 2);
  int*    srcs    = (int*)alloc((size_t)N_EDGES * 4);
  int*    eids    = (int*)alloc((size_t)N_EDGES * 4);
  float*  beff    = (float*)alloc((size_t)3 * 3 * 64 * 4);
  int*    row_ptr = (int*)alloc((N_NODES + 1) * 4);
  int*    cursor  = (int*)alloc((size_t)N_NODES * 4);
  int*    cnt     = (int*)alloc((size_t)N_NODES * 4);
  float*  log_deg = (float*)alloc((size_t)N_NODES * 4);
  int*    bsum    = (int*)alloc(256 * 4);
  int*    boff    = (int*)alloc(256 * 4);
  double* avgacc  = (double*)alloc(256);
  float*  avgf    = (float*)alloc(256);
  double* bnacc   = (double*)alloc(3 * 128 * 8);
  float*  gsum    = (float*)alloc((size_t)NGRAPH * 64 * 4);
  int*    gcnt    = (int*)alloc((size_t)NGRAPH * 4);

  zero_kernel<<<213, 256, 0, stream>>>(cnt, gsum, bnacc, avgacc);
  node_enc_kernel<<<12500, 256, 0, stream>>>(xin, node_w, node_b, x);
  count_kernel<<<3125, 256, 0, stream>>>(dstp, cnt);
  scan_a_kernel<<<196, 256, 0, stream>>>(cnt, bsum);
  scan_b_kernel<<<1, 256, 0, stream>>>(bsum, boff);
  scan_c_kernel<<<196, 256, 0, stream>>>(cnt, boff, row_ptr, cursor);
  fill_kernel<<<3125, 256, 0, stream>>>(srcp, dstp, cursor, srcs, eids);
  deg_log_kernel<<<196, 256, 0, stream>>>(cnt, log_deg, avgacc);
  avg_gb_kernel<<<1, 64, 0, stream>>>(avgacc, avgf, batch, gcnt);
  wprep_kernel<<<1296, 256, 0, stream>>>(conv_w, wh, wl);
  bprep_kernel<<<3, 192, 0, stream>>>(conv_w, beff);

  agg_e_kernel<<<12500, 256, 0, stream>>>(eattr, edge_w, edge_b, row_ptr,
                                          eids, agg_h, agg_l);

  for (int l = 0; l < 3; l++) {
    agg_x_kernel<<<12500, 256, 0, stream>>>(x, srcs, row_ptr, agg_h, agg_l);
    gemm_kernel<<<782, 256, 0, stream>>>(agg_h, agg_l,
                                         wh + (size_t)l * 12 * 72 * 128,
                                         wl + (size_t)l * 12 * 72 * 128,
                                         beff + l * 192, conv_b + l * 64,
                                         log_deg, avgf, h, bnacc + l * 128);
    apply_kernel<<<3125, 256, 0, stream>>>(h, bnacc + l * 128, bn_g + l * 64,
                                           bn_b + l * 64, x);
  }

  pool_kernel<<<782, 256, 0, stream>>>(x, batch, gsum);
  fc_kernel<<<1, 64, 0, stream>>>(gsum, gcnt, fc1_w, fc1_b, fc2_w, fc2_b,
                                  fc3_w, fc3_b, out);
}